// Round 1
// baseline (1225.788 us; speedup 1.0000x reference)
//
#include <hip/hip_runtime.h>
#include <math.h>

#define N 50000
#define E 600000
#define EPB 32     // edges per pass
#define LDK 104    // padded K stride (bf16 elems) for tp tiles

typedef __attribute__((ext_vector_type(8))) short short8;
typedef __attribute__((ext_vector_type(4))) float float4v;

__device__ __forceinline__ float silu_f(float x) { return x / (1.f + __expf(-x)); }
__device__ __forceinline__ float sigm_f(float x) { return 1.f / (1.f + __expf(-x)); }
__device__ __forceinline__ unsigned short f2bf(float f) {
  unsigned u = __float_as_uint(f);
  u += 0x7fff + ((u >> 16) & 1);   // RNE
  return (unsigned short)(u >> 16);
}
__device__ __forceinline__ float bf2f(unsigned short u) {
  return __uint_as_float(((unsigned)u) << 16);
}

// ---------------- CSR build ----------------
__global__ void k_hist(const int* __restrict__ eidx, int* __restrict__ counts) {
  int e = blockIdx.x * 256 + threadIdx.x;
  if (e < E) atomicAdd(&counts[eidx[E + e]], 1);
}

__global__ __launch_bounds__(1024)
void k_scan(const int* __restrict__ counts, int* __restrict__ row_ptr) {
  __shared__ int ssum[1024];
  const int t = threadIdx.x;
  const int CH = 49;
  int lo = t * CH, hi = min(lo + CH, N);
  int s = 0;
  for (int i = lo; i < hi; i++) s += counts[i];
  ssum[t] = s;
  __syncthreads();
  for (int off = 1; off < 1024; off <<= 1) {
    int v = (t >= off) ? ssum[t - off] : 0;
    __syncthreads();
    ssum[t] += v;
    __syncthreads();
  }
  int run = (t == 0) ? 0 : ssum[t - 1];
  for (int i = lo; i < hi; i++) { row_ptr[i] = run; run += counts[i]; }
  if (t == 1023) row_ptr[N] = ssum[1023];
}

// epos[e] = CSR slot of edge e (inverse permutation): k_msg scatters messages
// directly into CSR order so k_agg reads are fully sequential.
__global__ void k_scatter(const int* __restrict__ eidx, const int* __restrict__ row_ptr,
                          int* __restrict__ woff, int* __restrict__ epos) {
  int e = blockIdx.x * 256 + threadIdx.x;
  if (e < E) {
    int d = eidx[E + e];
    int p = atomicAdd(&woff[d], 1);
    epos[e] = row_ptr[d] + p;
  }
}

// ---------------- weight prep: bf16 transposed B matrices for k_c1/k_c2 ----------------
__global__ void k_prep(const float* __restrict__ Wsc0, const float* __restrict__ W3s,
                       const float* __restrict__ Wsc1, const float* __restrict__ W3v,
                       unsigned short* __restrict__ BT, unsigned short* __restrict__ B2T) {
  int i = blockIdx.x * 256 + threadIdx.x;
  if (i < 96 * 1088) {
    int j = i / 1088, k = i % 1088;
    float v;
    if (k < 1024) v = Wsc0[(size_t)k * 96 + j] * 0.03125f;          // 1/sqrt(1024)
    else          v = W3s[(size_t)(k - 1024) * 96 + j] * 0.125f;    // 1/sqrt(64)
    BT[i] = f2bf(v);
  } else {
    int i2 = i - 96 * 1088;
    if (i2 < 32 * 576) {
      int w = i2 / 576, k = i2 % 576;
      float v = 0.f;
      if (k < 512)      v = Wsc1[(size_t)k * 32 + w] * 0.04419417382415922f;  // 1/sqrt(512)
      else if (k < 544) v = W3v[(size_t)(k - 512) * 32 + w] * 0.17677669529663689f; // 1/sqrt(32)
      B2T[i2] = f2bf(v);
    }
  }
}

// ---------------- Kernel A: s1 = node_s@W1s/8 ; v1 = node_v x W1v /sqrt(32) ----------------
__global__ __launch_bounds__(256, 4)
void k_lin1(const float* __restrict__ node_s, const float* __restrict__ node_v,
            const float* __restrict__ W1s, const float* __restrict__ W1v,
            float* __restrict__ s1, float* __restrict__ v1) {
  __shared__ float w1s[64 * 64];
  __shared__ float w1v[32 * 32];
  for (int i = threadIdx.x; i < 64 * 64; i += 256) w1s[i] = W1s[i];
  for (int i = threadIdx.x; i < 32 * 32; i += 256) w1v[i] = W1v[i];
  __syncthreads();
  const float is_ns = 0.125f;
  const float is_nv = 0.17677669529663689f;
  int gtid = blockIdx.x * 256 + threadIdx.x;
  int stride = gridDim.x * 256;
  for (int i = gtid; i < N * 160; i += stride) {
    int n = i / 160, ch = i % 160;
    if (ch < 64) {
      const float* row = node_s + n * 64;
      float acc = 0.f;
#pragma unroll
      for (int u = 0; u < 64; u++) acc += row[u] * w1s[u * 64 + ch];
      s1[n * 64 + ch] = acc * is_ns;
    } else {
      int p = ch - 64, v = p / 3, c = p % 3;
      const float* row = node_v + n * 96;
      float acc = 0.f;
#pragma unroll
      for (int u = 0; u < 32; u++) acc += row[u * 3 + c] * w1v[u * 32 + v];
      v1[n * 96 + p] = acc * is_nv;
    }
  }
}

// ---------------- Kernel B: streaming per-edge message via MFMA ----------------
// EPB=32 edges/pass, 512 threads (8 waves). GEMM1 (32x96, 12 tiles) and
// GEMM2 (96x32, 12 tiles) fused into ONE MFMA phase: 24 tiles over 8 waves
// = 3 tiles/wave, zero idle slots. Gates written to LDS in G1 epilogue,
// applied to register-held G2 accumulators after one sync.
// STORE=1: messages scattered to CSR slot epos[e] (k_agg streams sequentially)
// STORE=0: fallback, atomicAdd into aggs/aggv
template<int STORE>
__global__ __launch_bounds__(512, 4)
void k_msg(const float* __restrict__ s1, const float* __restrict__ v1,
           const float* __restrict__ emb, const float* __restrict__ sh0g,
           const float* __restrict__ sh1g, const int* __restrict__ eidx,
           const int* __restrict__ eposg,
           const float* __restrict__ Wm1, const float* __restrict__ Wm2,
           const float* __restrict__ W2s, const float* __restrict__ W2v,
           float* __restrict__ aggs, float* __restrict__ aggv,
           unsigned short* __restrict__ msgS, unsigned short* __restrict__ msgV) {
  __shared__ unsigned short w2sT[96 * LDK];   // W2sT[j][k] bf16 (isq96 folded)
  __shared__ unsigned short w2vT[32 * LDK];   // W2vT[v][k] bf16 (isq96 folded)
  __shared__ float wm2s[192 * 9];             // staging, stride 9 (bank-safe)
  __shared__ float wm1s[64];
  __shared__ unsigned short tps[EPB * LDK];        // 32 rows
  __shared__ unsigned short tpv[EPB * 3 * LDK];    // 96 rows
  __shared__ float gat[EPB][33];              // padded: bank-conflict-free
  __shared__ float hb[EPB][8];
  __shared__ float sh1b[EPB][4];
  __shared__ float sh0b[EPB];
  __shared__ int ssrc[EPB];
  __shared__ int sdst[EPB];
  __shared__ int spos[EPB];

  const int t = threadIdx.x;
  const int wave = t >> 6, lane = t & 63;
  const int lm = lane & 15, quad = lane >> 4;
  const float isq96 = 0.10206207261596575f;

  // ---- one-time staging ----
  for (int i = t; i < 96 * 96; i += 512) {
    int k = i / 96, j = i % 96;
    w2sT[j * LDK + k] = f2bf(W2s[i] * isq96);
  }
  for (int i = t; i < 96 * 32; i += 512) {
    int u = i / 32, v = i % 32;
    w2vT[v * LDK + u] = f2bf(W2v[i] * isq96);
  }
  for (int i = t; i < 192 * 8; i += 512) {
    int h = i / 192, c = i % 192;
    wm2s[c * 9 + h] = Wm2[i];
  }
  if (t < 64) wm1s[t] = Wm1[t];
  __syncthreads();
  // register-cache this thread's 12 Wm2 rows (fixed by sub across all passes)
  const int subc = t & 15;
  float wA0[4][8], wA1[4][8], wB1[2][8], wB0[2][8];
#pragma unroll
  for (int i = 0; i < 4; i++)
#pragma unroll
    for (int h = 0; h < 8; h++) {
      wA0[i][h] = wm2s[(subc * 4 + i) * 9 + h];
      wA1[i][h] = wm2s[(64 + subc * 4 + i) * 9 + h];
    }
#pragma unroll
  for (int i2 = 0; i2 < 2; i2++)
#pragma unroll
    for (int h = 0; h < 8; h++) {
      wB1[i2][h] = wm2s[(128 + subc * 2 + i2) * 9 + h];
      wB0[i2][h] = wm2s[(160 + subc * 2 + i2) * 9 + h];
    }

  for (int pass = blockIdx.x; pass < E / EPB; pass += gridDim.x) {
    const int ebase = pass * EPB;
    __syncthreads();   // prev phase D (reads gat/spos/sdst) done before A overwrites
    // ---- phase A: stage edge meta + radial MLP hidden (disjoint threads) ----
    if (t < EPB) {
      ssrc[t] = eidx[ebase + t];
      sh0b[t] = sh0g[ebase + t];
      if (STORE) spos[t] = eposg[ebase + t];
      else       sdst[t] = eidx[E + ebase + t];
    } else if (t >= 64 && t < 64 + EPB * 3) {
      int i = t - 64;
      sh1b[i / 3][i % 3] = sh1g[ebase * 3 + i];
    } else if (t >= 256) {
      int i = t - 256, el = i >> 3, sub = i & 7;
      float acc = 0.f;
#pragma unroll
      for (int r = 0; r < 8; r++) acc += emb[(ebase + el) * 8 + r] * wm1s[r * 8 + sub];
      hb[el][sub] = silu_f(acc);
    }
    __syncthreads();
    // ---- phase B: build TPS / TPV (bf16), weights all in registers ----
    {
      const int el = t >> 4, sub = subc;
      const int src = ssrc[el];
      const float s0v = sh0b[el];
      const float x0 = sh1b[el][0], x1 = sh1b[el][1], x2 = sh1b[el][2];
      float hr[8];
#pragma unroll
      for (int h = 0; h < 8; h++) hr[h] = hb[el][h];
      const float4v ss = *(const float4v*)&s1[(size_t)src * 64 + sub * 4];
      unsigned short tsv[4], tvv[3][4];
#pragma unroll
      for (int i = 0; i < 4; i++) {
        float w0a = 0.f, w1a = 0.f;
#pragma unroll
        for (int h = 0; h < 8; h++) {
          w0a += hr[h] * wA0[i][h];
          w1a += hr[h] * wA1[i][h];
        }
        const float ssu = ss[i];
        tsv[i] = f2bf(w0a * ssu * s0v);
        const float base = w1a * ssu;
        tvv[0][i] = f2bf(base * x0);
        tvv[1][i] = f2bf(base * x1);
        tvv[2][i] = f2bf(base * x2);
      }
      *(uint2*)&tps[el * LDK + sub * 4] = *(uint2*)tsv;
#pragma unroll
      for (int c = 0; c < 3; c++)
        *(uint2*)&tpv[(el * 3 + c) * LDK + sub * 4] = *(uint2*)tvv[c];
      const float2* vp = (const float2*)&v1[(size_t)src * 96 + sub * 6];
      const float2 va = vp[0], vb = vp[1], vc = vp[2];
      const float v6[6] = {va.x, va.y, vb.x, vb.y, vc.x, vc.y};
      unsigned short ts2[2], tv2[3][2];
#pragma unroll
      for (int i2 = 0; i2 < 2; i2++) {
        float w1b = 0.f, w0b = 0.f;
#pragma unroll
        for (int h = 0; h < 8; h++) {
          w1b += hr[h] * wB1[i2][h];
          w0b += hr[h] * wB0[i2][h];
        }
        const float vx = v6[i2 * 3 + 0], vy = v6[i2 * 3 + 1], vz = v6[i2 * 3 + 2];
        ts2[i2] = f2bf(w0b * (vx * x0 + vy * x1 + vz * x2));
        tv2[0][i2] = f2bf(w1b * vx * s0v);
        tv2[1][i2] = f2bf(w1b * vy * s0v);
        tv2[2][i2] = f2bf(w1b * vz * s0v);
      }
      *(unsigned*)&tps[el * LDK + 64 + sub * 2] = *(unsigned*)ts2;
#pragma unroll
      for (int c = 0; c < 3; c++)
        *(unsigned*)&tpv[(el * 3 + c) * LDK + 64 + sub * 2] = *(unsigned*)tv2[c];
    }
    __syncthreads();
    // ---- phase C: all 24 MFMA tiles (12 G1 + 12 G2), 3 per wave ----
    float4v acc2[3];
#pragma unroll
    for (int tt = 0; tt < 3; tt++) {
      const int id = wave + tt * 8;
      float4v acc = {0.f, 0.f, 0.f, 0.f};
      if (id < 12) {
        // GEMM1 tile: m_s[32][96]
        const int mt = id / 6, nt = id % 6;
#pragma unroll
        for (int kk = 0; kk < 3; kk++) {
          short8 a = *(const short8*)&tps[(mt * 16 + lm) * LDK + kk * 32 + quad * 8];
          short8 b = *(const short8*)&w2sT[(nt * 16 + lm) * LDK + kk * 32 + quad * 8];
          acc = __builtin_amdgcn_mfma_f32_16x16x32_bf16(a, b, acc, 0, 0, 0);
        }
        const int j = nt * 16 + lm;
#pragma unroll
        for (int reg = 0; reg < 4; reg++) {
          const int e = mt * 16 + quad * 4 + reg;
          const float val = acc[reg];
          if (j < 64) {
            if (STORE) msgS[(size_t)spos[e] * 64 + j] = f2bf(silu_f(val));
            else atomicAdd(&aggs[(size_t)sdst[e] * 64 + j], silu_f(val));
          } else {
            gat[e][j - 64] = sigm_f(val);
          }
        }
      } else {
        // GEMM2 tile: m_v[96][32], gate applied after sync
        const int id2 = id - 12;
        const int mt = id2 >> 1, nt2 = id2 & 1;
#pragma unroll
        for (int kk = 0; kk < 3; kk++) {
          short8 a = *(const short8*)&tpv[(mt * 16 + lm) * LDK + kk * 32 + quad * 8];
          short8 b = *(const short8*)&w2vT[(nt2 * 16 + lm) * LDK + kk * 32 + quad * 8];
          acc = __builtin_amdgcn_mfma_f32_16x16x32_bf16(a, b, acc, 0, 0, 0);
        }
        acc2[tt] = acc;
      }
    }
    __syncthreads();
    // ---- phase D: gate + store m_v ----
#pragma unroll
    for (int tt = 0; tt < 3; tt++) {
      const int id = wave + tt * 8;
      if (id >= 12) {
        const int id2 = id - 12;
        const int mt = id2 >> 1, nt2 = id2 & 1;
        const int v = nt2 * 16 + lm;
#pragma unroll
        for (int reg = 0; reg < 4; reg++) {
          const int r = mt * 16 + quad * 4 + reg;
          const int e = (r * 171) >> 9, c = r - 3 * e;
          const float val = acc2[tt][reg] * gat[e][v];
          if (STORE) msgV[(size_t)spos[e] * 96 + v * 3 + c] = f2bf(val);
          else atomicAdd(&aggv[(size_t)sdst[e] * 96 + v * 3 + c], val);
        }
      }
    }
  }
}

// ---------------- Kernel B2: wave-per-node streaming reduction (CSR order) ----------------
__global__ __launch_bounds__(256, 8)
void k_agg(const unsigned short* __restrict__ msgS, const unsigned short* __restrict__ msgV,
           const int* __restrict__ rowp,
           float* __restrict__ aggs, float* __restrict__ aggv) {
  const int wv = threadIdx.x >> 6, lane = threadIdx.x & 63;
  const int n = blockIdx.x * 4 + wv;
  const int lo = rowp[n], hi = rowp[n + 1];
  float sS = 0.f, v0 = 0.f, v1a = 0.f;
  int r = lo;
  for (; r + 2 <= hi; r += 2) {
    const unsigned short a0 = msgS[(size_t)r * 64 + lane];
    const unsigned short a1 = msgS[(size_t)(r + 1) * 64 + lane];
    const unsigned short b0 = msgV[(size_t)r * 96 + lane];
    const unsigned short b1 = msgV[(size_t)(r + 1) * 96 + lane];
    unsigned short c0 = 0, c1 = 0;
    if (lane < 32) {
      c0 = msgV[(size_t)r * 96 + 64 + lane];
      c1 = msgV[(size_t)(r + 1) * 96 + 64 + lane];
    }
    sS += bf2f(a0) + bf2f(a1);
    v0 += bf2f(b0) + bf2f(b1);
    v1a += bf2f(c0) + bf2f(c1);
  }
  for (; r < hi; r++) {
    sS += bf2f(msgS[(size_t)r * 64 + lane]);
    v0 += bf2f(msgV[(size_t)r * 96 + lane]);
    if (lane < 32) v1a += bf2f(msgV[(size_t)r * 96 + 64 + lane]);
  }
  aggs[(size_t)n * 64 + lane] = sS;
  aggv[(size_t)n * 96 + lane] = v0;
  if (lane < 32) aggv[(size_t)n * 96 + 64 + lane] = v1a;
}

// ---------------- Kernel C1: MFMA GEMM  [32 nodes x 1088] @ BT^T -> 96 cols ----------------
__global__ __launch_bounds__(256, 4)
void k_c1(const float* __restrict__ node_s, const float* __restrict__ attrs,
          const float* __restrict__ aggs, const float* __restrict__ Wt0,
          const unsigned short* __restrict__ BT,
          float* __restrict__ out, float* __restrict__ gates) {
  __shared__ float s_row[32][64];
  __shared__ float attr[32][16];
  __shared__ float t0[32][64];
  __shared__ float wt0[1024];
  __shared__ unsigned short As[32 * 72];
  const int t = threadIdx.x;
  const int wave = t >> 6, lane = t & 63, lm = lane & 15, quad = lane >> 4;
  const int nbase = blockIdx.x * 32;

  for (int i = t; i < 1024; i += 256) wt0[i] = Wt0[i];
  for (int i = t; i < 2048; i += 256) {
    int nl = i >> 6, u = i & 63, n = nbase + nl;
    s_row[nl][u] = (n < N) ? node_s[(size_t)n * 64 + u] : 0.f;
    t0[nl][u]    = (n < N) ? aggs[(size_t)n * 64 + u] : 0.f;
  }
  for (int i = t; i < 512; i += 256) {
    int nl = i >> 4, a = i & 15, n = nbase + nl;
    attr[nl][a] = (n < N) ? attrs[(size_t)n * 16 + a] : 0.f;
  }
  __syncthreads();
  for (int i = t; i < 2048; i += 256) {
    int nl = i >> 6, u = i & 63;
    float d0 = 0.f;
#pragma unroll
    for (int a = 0; a < 16; a++) d0 += attr[nl][a] * wt0[u * 16 + a];
    t0[nl][u] *= d0 * 0.07216878364870322f;   // 1/(sqrt(16)*sqrt(12))
  }

  float4v acc[3] = {{0,0,0,0},{0,0,0,0},{0,0,0,0}};
  int mts[3], nts[3];
#pragma unroll
  for (int tt = 0; tt < 3; tt++) {
    const int tile = wave + tt * 4;    // 0..11 = mt*6+nt
    mts[tt] = tile / 6;
    nts[tt] = tile % 6;
  }

  for (int kc = 0; kc < 17; kc++) {
    __syncthreads();
    {
      const int row = t >> 3, c0 = (t & 7) * 8;
      unsigned short tmp[8];
      if (kc < 16) {
        const int u = kc * 4 + (c0 >> 4);
        const float sval = s_row[row][u];
        const int ab = c0 & 8;
#pragma unroll
        for (int i = 0; i < 8; i++) tmp[i] = f2bf(sval * attr[row][ab + i]);
      } else {
#pragma unroll
        for (int i = 0; i < 8; i++) tmp[i] = f2bf(t0[row][c0 + i]);
      }
      *(uint4*)&As[row * 72 + c0] = *(uint4*)tmp;
    }
    __syncthreads();
#pragma unroll
    for (int ks = 0; ks < 2; ks++) {
      short8 am0 = *(const short8*)&As[(lm) * 72 + ks * 32 + quad * 8];
      short8 am1 = *(const short8*)&As[(16 + lm) * 72 + ks * 32 + quad * 8];
#pragma unroll
      for (int tt = 0; tt < 3; tt++) {
        short8 b = *(const short8*)&BT[(size_t)(nts[tt] * 16 + lm) * 1088 + kc * 64 + ks * 32 + quad * 8];
        acc[tt] = __builtin_amdgcn_mfma_f32_16x16x32_bf16(mts[tt] ? am1 : am0, b, acc[tt], 0, 0, 0);
      }
    }
  }
#pragma unroll
  for (int tt = 0; tt < 3; tt++) {
    const int j = nts[tt] * 16 + lm;
#pragma unroll
    for (int reg = 0; reg < 4; reg++) {
      const int m = mts[tt] * 16 + quad * 4 + reg;
      const int n = nbase + m;
      if (n < N) {
        const float val = acc[tt][reg];
        if (j < 64) out[(size_t)n * 160 + j] = silu_f(val);
        else        gates[(size_t)n * 32 + (j - 64)] = sigm_f(val);
      }
    }
  }
}

// ---------------- Kernel C2: MFMA GEMM  [96 rows (32n x 3c) x 544] @ B2T^T -> 32 cols ----------------
__global__ __launch_bounds__(256, 3)
void k_c2(const float* __restrict__ node_v, const float* __restrict__ attrs,
          const float* __restrict__ aggv, const float* __restrict__ Wt1,
          const unsigned short* __restrict__ B2T, const float* __restrict__ gts,
          float* __restrict__ out) {
  __shared__ float nvs[32][96];
  __shared__ float t1s[32][96];
  __shared__ float attr[32][16];
  __shared__ float wt1[512];
  __shared__ unsigned short As2[96 * 72];
  const int t = threadIdx.x;
  const int wave = t >> 6, lane = t & 63, lm = lane & 15, quad = lane >> 4;
  const int nbase = blockIdx.x * 32;

  for (int i = t; i < 512; i += 256) wt1[i] = Wt1[i];
  for (int i = t; i < 32 * 96; i += 256) {
    int nl = i / 96, rr = i % 96, n = nbase + nl;
    nvs[nl][rr] = (n < N) ? node_v[(size_t)n * 96 + rr] : 0.f;
    t1s[nl][rr] = (n < N) ? aggv[(size_t)n * 96 + rr] : 0.f;
  }
  for (int i = t; i < 512; i += 256) {
    int nl = i >> 4, a = i & 15, n = nbase + nl;
    attr[nl][a] = (n < N) ? attrs[(size_t)n * 16 + a] : 0.f;
  }
  __syncthreads();
  for (int i = t; i < 1024; i += 256) {
    int nl = i >> 5, u = i & 31;
    float d1 = 0.f;
#pragma unroll
    for (int a = 0; a < 16; a++) d1 += attr[nl][a] * wt1[u * 16 + a];
    d1 *= 0.07216878364870322f;
    t1s[nl][u * 3 + 0] *= d1; t1s[nl][u * 3 + 1] *= d1; t1s[nl][u * 3 + 2] *= d1;
  }

  float4v acc[3] = {{0,0,0,0},{0,0,0,0},{0,0,0,0}};
  int mts[3], nts[3];
#pragma unroll
  for (int tt = 0; tt < 3; tt++) {
    const int tile = wave + tt * 4;   // 0..11 = mt*2+nt
    mts[tt] = tile >> 1;
    nts[tt] = tile & 1;
  }

  for (int kc = 0; kc < 9; kc++) {
    __syncthreads();
#pragma unroll
    for (int jj = 0; jj < 3; jj++) {
      const int job = t + jj * 256;
      const int row = job >> 3, c0 = (job & 7) * 8;
      const int nl = (row * 171) >> 9, c = row - 3 * nl;
      const int kbase = kc * 64 + c0;
      unsigned short tmp[8];
      if (kbase < 512) {
        const int u = kbase >> 4;
        const float vval = nvs[nl][u * 3 + c];
        const int ab = c0 & 8;
#pragma unroll
        for (int i = 0; i < 8; i++) tmp[i] = f2bf(vval * attr[nl][ab + i]);
      } else if (kbase < 544) {
        const int u2 = kbase - 512;
#pragma unroll
        for (int i = 0; i < 8; i++) tmp[i] = f2bf(t1s[nl][(u2 + i) * 3 + c]);
      } else {
#pragma unroll
        for (int i = 0; i < 8; i++) tmp[i] = 0;
      }
      *(uint4*)&As2[row * 72 + c0] = *(uint4*)tmp;
    }
    __syncthreads();
#pragma unroll
    for (int ks = 0; ks < 2; ks++) {
#pragma unroll
      for (int tt = 0; tt < 3; tt++) {
        short8 a = *(const short8*)&As2[(mts[tt] * 16 + lm) * 72 + ks * 32 + quad * 8];
        short8 b = *(const short8*)&B2T[(size_t)(nts[tt] * 16 + lm) * 576 + kc * 64 + ks * 32 + quad * 8];
        acc[tt] = __builtin_amdgcn_mfma_f32_16x16x32_bf16(a, b, acc[tt], 0, 0, 0);
      }
    }
  }
#pragma unroll
  for (int tt = 0; tt < 3; tt++) {
    const int w = nts[tt] * 16 + lm;
#pragma unroll
    for (int reg = 0; reg < 4; reg++) {
      const int row = mts[tt] * 16 + quad * 4 + reg;
      const int nl = (row * 171) >> 9, c = row - 3 * nl;
      const int n = nbase + nl;
      if (n < N)
        out[(size_t)n * 160 + 64 + w * 3 + c] = acc[tt][reg] * gts[(size_t)n * 32 + w];
    }
  }
}

extern "C" void kernel_launch(void* const* d_in, const int* in_sizes, int n_in,
                              void* d_out, int out_size, void* d_ws, size_t ws_size,
                              hipStream_t stream) {
  const float* node_s = (const float*)d_in[0];
  const float* node_v = (const float*)d_in[1];
  const float* attrs  = (const float*)d_in[2];
  const float* emb    = (const float*)d_in[3];
  const float* sh0    = (const float*)d_in[4];
  const float* sh1    = (const float*)d_in[5];
  const int*   eidx   = (const int*)d_in[6];
  const float* W1s    = (const float*)d_in[7];
  const float* W1v    = (const float*)d_in[8];
  const float* Wm1    = (const float*)d_in[9];
  const float* Wm2    = (const float*)d_in[10];
  const float* W2s    = (const float*)d_in[11];
  const float* W2v    = (const float*)d_in[12];
  const float* Wt0    = (const float*)d_in[13];
  const float* Wt1    = (const float*)d_in[14];
  const float* W3s    = (const float*)d_in[15];
  const float* W3v    = (const float*)d_in[16];
  const float* Wsc0   = (const float*)d_in[17];
  const float* Wsc1   = (const float*)d_in[18];

  char* p = (char*)d_ws;
  float* s1  = (float*)p;  p += (size_t)N * 64 * 4;
  float* v1f = (float*)p;  p += (size_t)N * 96 * 4;
  float* gts = (float*)p;  p += (size_t)N * 32 * 4;
  unsigned short* BT  = (unsigned short*)p;  p += (size_t)96 * 1088 * 2;
  unsigned short* B2T = (unsigned short*)p;  p += (size_t)32 * 576 * 2;
  char* pmode = p;
  size_t base = (size_t)(pmode - (char*)d_ws);
  size_t need_store = base + ((size_t)N + 1) * 4 + (size_t)N * 4 + (size_t)E * 4
                    + (size_t)E * 64 * 2 + (size_t)E * 96 * 2;
  const bool store = (ws_size >= need_store);

  k_prep<<<480, 256, 0, stream>>>(Wsc0, W3s, Wsc1, W3v, BT, B2T);
  k_lin1<<<1024, 256, 0, stream>>>(node_s, node_v, W1s, W1v, s1, v1f);

  if (store) {
    int* rowp = (int*)pmode;
    int* cnt  = rowp + (N + 1);
    int* epos = cnt + N;
    unsigned short* msgS = (unsigned short*)(epos + E);
    unsigned short* msgV = msgS + (size_t)E * 64;
    hipMemsetAsync(cnt, 0, (size_t)N * 4, stream);
    k_hist<<<(E + 255) / 256, 256, 0, stream>>>(eidx, cnt);
    k_scan<<<1, 1024, 0, stream>>>(cnt, rowp);
    hipMemsetAsync(cnt, 0, (size_t)N * 4, stream);
    k_scatter<<<(E + 255) / 256, 256, 0, stream>>>(eidx, rowp, cnt, epos);
    k_msg<1><<<512, 512, 0, stream>>>(s1, v1f, emb, sh0, sh1, eidx, epos, Wm1, Wm2, W2s, W2v,
                                      nullptr, nullptr, msgS, msgV);
    float* aggs = s1;    // s1/v1 dead after k_msg: alias
    float* aggv = v1f;
    k_agg<<<N / 4, 256, 0, stream>>>(msgS, msgV, rowp, aggs, aggv);
    k_c1<<<1563, 256, 0, stream>>>(node_s, attrs, aggs, Wt0, BT, (float*)d_out, gts);
    k_c2<<<1563, 256, 0, stream>>>(node_v, attrs, aggv, Wt1, B2T, gts, (float*)d_out);
  } else {
    float* aggs = (float*)pmode;
    float* aggv = aggs + (size_t)N * 64;
    hipMemsetAsync(aggs, 0, (size_t)N * 160 * 4, stream);
    k_msg<0><<<512, 512, 0, stream>>>(s1, v1f, emb, sh0, sh1, eidx, nullptr, Wm1, Wm2, W2s, W2v,
                                      aggs, aggv, nullptr, nullptr);
    k_c1<<<1563, 256, 0, stream>>>(node_s, attrs, aggs, Wt0, BT, (float*)d_out, gts);
    k_c2<<<1563, 256, 0, stream>>>(node_v, attrs, aggv, Wt1, B2T, gts, (float*)d_out);
  }
}

// Round 2
// 1160.861 us; speedup vs baseline: 1.0559x; 1.0559x over previous
//
#include <hip/hip_runtime.h>
#include <math.h>

#define N 50000
#define E 600000
#define EPB 32     // edges per pass
#define LDK 104    // padded K stride (bf16 elems) for tp tiles

typedef __attribute__((ext_vector_type(8))) short short8;
typedef __attribute__((ext_vector_type(4))) float float4v;

__device__ __forceinline__ float silu_f(float x) { return x / (1.f + __expf(-x)); }
__device__ __forceinline__ float sigm_f(float x) { return 1.f / (1.f + __expf(-x)); }
__device__ __forceinline__ unsigned short f2bf(float f) {
  unsigned u = __float_as_uint(f);
  u += 0x7fff + ((u >> 16) & 1);   // RNE
  return (unsigned short)(u >> 16);
}
__device__ __forceinline__ float bf2f(unsigned short u) {
  return __uint_as_float(((unsigned)u) << 16);
}

// ---------------- CSR build ----------------
__global__ void k_hist(const int* __restrict__ eidx, int* __restrict__ counts) {
  int e = blockIdx.x * 256 + threadIdx.x;
  if (e < E) atomicAdd(&counts[eidx[E + e]], 1);
}

__global__ __launch_bounds__(1024)
void k_scan(const int* __restrict__ counts, int* __restrict__ row_ptr) {
  __shared__ int ssum[1024];
  const int t = threadIdx.x;
  const int CH = 49;
  int lo = t * CH, hi = min(lo + CH, N);
  int s = 0;
  for (int i = lo; i < hi; i++) s += counts[i];
  ssum[t] = s;
  __syncthreads();
  for (int off = 1; off < 1024; off <<= 1) {
    int v = (t >= off) ? ssum[t - off] : 0;
    __syncthreads();
    ssum[t] += v;
    __syncthreads();
  }
  int run = (t == 0) ? 0 : ssum[t - 1];
  for (int i = lo; i < hi; i++) { row_ptr[i] = run; run += counts[i]; }
  if (t == 1023) row_ptr[N] = ssum[1023];
}

// perm[slot] = edge id: k_msg writes messages in EDGE order (coalesced,
// full-line writes -> no write-allocate fetches); k_agg gathers via perm.
__global__ void k_scatter(const int* __restrict__ eidx, const int* __restrict__ row_ptr,
                          int* __restrict__ woff, int* __restrict__ perm) {
  int e = blockIdx.x * 256 + threadIdx.x;
  if (e < E) {
    int d = eidx[E + e];
    int p = atomicAdd(&woff[d], 1);
    perm[row_ptr[d] + p] = e;
  }
}

// ---------------- weight prep: bf16 transposed B matrices for k_c1/k_c2 ----------------
__global__ void k_prep(const float* __restrict__ Wsc0, const float* __restrict__ W3s,
                       const float* __restrict__ Wsc1, const float* __restrict__ W3v,
                       unsigned short* __restrict__ BT, unsigned short* __restrict__ B2T) {
  int i = blockIdx.x * 256 + threadIdx.x;
  if (i < 96 * 1088) {
    int j = i / 1088, k = i % 1088;
    float v;
    if (k < 1024) v = Wsc0[(size_t)k * 96 + j] * 0.03125f;          // 1/sqrt(1024)
    else          v = W3s[(size_t)(k - 1024) * 96 + j] * 0.125f;    // 1/sqrt(64)
    BT[i] = f2bf(v);
  } else {
    int i2 = i - 96 * 1088;
    if (i2 < 32 * 576) {
      int w = i2 / 576, k = i2 % 576;
      float v = 0.f;
      if (k < 512)      v = Wsc1[(size_t)k * 32 + w] * 0.04419417382415922f;  // 1/sqrt(512)
      else if (k < 544) v = W3v[(size_t)(k - 512) * 32 + w] * 0.17677669529663689f; // 1/sqrt(32)
      B2T[i2] = f2bf(v);
    }
  }
}

// ---------------- Kernel A: s1 = node_s@W1s/8 ; v1 = node_v x W1v /sqrt(32) ----------------
__global__ __launch_bounds__(256, 4)
void k_lin1(const float* __restrict__ node_s, const float* __restrict__ node_v,
            const float* __restrict__ W1s, const float* __restrict__ W1v,
            float* __restrict__ s1, float* __restrict__ v1) {
  __shared__ float w1s[64 * 64];
  __shared__ float w1v[32 * 32];
  for (int i = threadIdx.x; i < 64 * 64; i += 256) w1s[i] = W1s[i];
  for (int i = threadIdx.x; i < 32 * 32; i += 256) w1v[i] = W1v[i];
  __syncthreads();
  const float is_ns = 0.125f;
  const float is_nv = 0.17677669529663689f;
  int gtid = blockIdx.x * 256 + threadIdx.x;
  int stride = gridDim.x * 256;
  for (int i = gtid; i < N * 160; i += stride) {
    int n = i / 160, ch = i % 160;
    if (ch < 64) {
      const float* row = node_s + n * 64;
      float acc = 0.f;
#pragma unroll
      for (int u = 0; u < 64; u++) acc += row[u] * w1s[u * 64 + ch];
      s1[n * 64 + ch] = acc * is_ns;
    } else {
      int p = ch - 64, v = p / 3, c = p % 3;
      const float* row = node_v + n * 96;
      float acc = 0.f;
#pragma unroll
      for (int u = 0; u < 32; u++) acc += row[u * 3 + c] * w1v[u * 32 + v];
      v1[n * 96 + p] = acc * is_nv;
    }
  }
}

// ---------------- Kernel B: streaming per-edge message via MFMA ----------------
// EPB=32 edges/pass, 512 threads (8 waves). GEMM1 (32x96, 12 tiles) and
// GEMM2 (96x32, 12 tiles) fused into ONE MFMA phase: 24 tiles over 8 waves
// = 3 tiles/wave, zero idle slots. Gates written to LDS in G1 epilogue,
// applied to register-held G2 accumulators after one sync.
// STORE=1: coalesced bf16 messages in EDGE order (k_agg gathers via perm) --
//   CSR-slot scatter writes were tried and regress 2.3x: random 32B
//   fragments onto 128/192B lines => write-allocate FETCH explosion (5.4x).
// STORE=0: fallback, atomicAdd into aggs/aggv
template<int STORE>
__global__ __launch_bounds__(512, 4)
void k_msg(const float* __restrict__ s1, const float* __restrict__ v1,
           const float* __restrict__ emb, const float* __restrict__ sh0g,
           const float* __restrict__ sh1g, const int* __restrict__ eidx,
           const float* __restrict__ Wm1, const float* __restrict__ Wm2,
           const float* __restrict__ W2s, const float* __restrict__ W2v,
           float* __restrict__ aggs, float* __restrict__ aggv,
           unsigned short* __restrict__ msgS, unsigned short* __restrict__ msgV) {
  __shared__ unsigned short w2sT[96 * LDK];   // W2sT[j][k] bf16 (isq96 folded)
  __shared__ unsigned short w2vT[32 * LDK];   // W2vT[v][k] bf16 (isq96 folded)
  __shared__ float wm2s[192 * 9];             // staging, stride 9 (bank-safe)
  __shared__ float wm1s[64];
  __shared__ unsigned short tps[EPB * LDK];        // 32 rows
  __shared__ unsigned short tpv[EPB * 3 * LDK];    // 96 rows
  __shared__ float gat[EPB][33];              // padded: bank-conflict-free
  __shared__ float hb[EPB][8];
  __shared__ float sh1b[EPB][4];
  __shared__ float sh0b[EPB];
  __shared__ int ssrc[EPB];
  __shared__ int sdst[EPB];

  const int t = threadIdx.x;
  const int wave = t >> 6, lane = t & 63;
  const int lm = lane & 15, quad = lane >> 4;
  const float isq96 = 0.10206207261596575f;

  // ---- one-time staging ----
  for (int i = t; i < 96 * 96; i += 512) {
    int k = i / 96, j = i % 96;
    w2sT[j * LDK + k] = f2bf(W2s[i] * isq96);
  }
  for (int i = t; i < 96 * 32; i += 512) {
    int u = i / 32, v = i % 32;
    w2vT[v * LDK + u] = f2bf(W2v[i] * isq96);
  }
  for (int i = t; i < 192 * 8; i += 512) {
    int h = i / 192, c = i % 192;
    wm2s[c * 9 + h] = Wm2[i];
  }
  if (t < 64) wm1s[t] = Wm1[t];
  __syncthreads();
  // register-cache this thread's 12 Wm2 rows (fixed by sub across all passes)
  const int subc = t & 15;
  float wA0[4][8], wA1[4][8], wB1[2][8], wB0[2][8];
#pragma unroll
  for (int i = 0; i < 4; i++)
#pragma unroll
    for (int h = 0; h < 8; h++) {
      wA0[i][h] = wm2s[(subc * 4 + i) * 9 + h];
      wA1[i][h] = wm2s[(64 + subc * 4 + i) * 9 + h];
    }
#pragma unroll
  for (int i2 = 0; i2 < 2; i2++)
#pragma unroll
    for (int h = 0; h < 8; h++) {
      wB1[i2][h] = wm2s[(128 + subc * 2 + i2) * 9 + h];
      wB0[i2][h] = wm2s[(160 + subc * 2 + i2) * 9 + h];
    }

  for (int pass = blockIdx.x; pass < E / EPB; pass += gridDim.x) {
    const int ebase = pass * EPB;
    __syncthreads();   // prev phase D (reads gat/sdst) done before A overwrites
    // ---- phase A: stage edge meta + radial MLP hidden (disjoint threads) ----
    if (t < EPB) {
      ssrc[t] = eidx[ebase + t];
      sh0b[t] = sh0g[ebase + t];
      if (!STORE) sdst[t] = eidx[E + ebase + t];
    } else if (t >= 64 && t < 64 + EPB * 3) {
      int i = t - 64;
      sh1b[i / 3][i % 3] = sh1g[ebase * 3 + i];
    } else if (t >= 256) {
      int i = t - 256, el = i >> 3, sub = i & 7;
      float acc = 0.f;
#pragma unroll
      for (int r = 0; r < 8; r++) acc += emb[(ebase + el) * 8 + r] * wm1s[r * 8 + sub];
      hb[el][sub] = silu_f(acc);
    }
    __syncthreads();
    // ---- phase B: build TPS / TPV (bf16), weights all in registers ----
    {
      const int el = t >> 4, sub = subc;
      const int src = ssrc[el];
      const float s0v = sh0b[el];
      const float x0 = sh1b[el][0], x1 = sh1b[el][1], x2 = sh1b[el][2];
      float hr[8];
#pragma unroll
      for (int h = 0; h < 8; h++) hr[h] = hb[el][h];
      const float4v ss = *(const float4v*)&s1[(size_t)src * 64 + sub * 4];
      unsigned short tsv[4], tvv[3][4];
#pragma unroll
      for (int i = 0; i < 4; i++) {
        float w0a = 0.f, w1a = 0.f;
#pragma unroll
        for (int h = 0; h < 8; h++) {
          w0a += hr[h] * wA0[i][h];
          w1a += hr[h] * wA1[i][h];
        }
        const float ssu = ss[i];
        tsv[i] = f2bf(w0a * ssu * s0v);
        const float base = w1a * ssu;
        tvv[0][i] = f2bf(base * x0);
        tvv[1][i] = f2bf(base * x1);
        tvv[2][i] = f2bf(base * x2);
      }
      *(uint2*)&tps[el * LDK + sub * 4] = *(uint2*)tsv;
#pragma unroll
      for (int c = 0; c < 3; c++)
        *(uint2*)&tpv[(el * 3 + c) * LDK + sub * 4] = *(uint2*)tvv[c];
      const float2* vp = (const float2*)&v1[(size_t)src * 96 + sub * 6];
      const float2 va = vp[0], vb = vp[1], vc = vp[2];
      const float v6[6] = {va.x, va.y, vb.x, vb.y, vc.x, vc.y};
      unsigned short ts2[2], tv2[3][2];
#pragma unroll
      for (int i2 = 0; i2 < 2; i2++) {
        float w1b = 0.f, w0b = 0.f;
#pragma unroll
        for (int h = 0; h < 8; h++) {
          w1b += hr[h] * wB1[i2][h];
          w0b += hr[h] * wB0[i2][h];
        }
        const float vx = v6[i2 * 3 + 0], vy = v6[i2 * 3 + 1], vz = v6[i2 * 3 + 2];
        ts2[i2] = f2bf(w0b * (vx * x0 + vy * x1 + vz * x2));
        tv2[0][i2] = f2bf(w1b * vx * s0v);
        tv2[1][i2] = f2bf(w1b * vy * s0v);
        tv2[2][i2] = f2bf(w1b * vz * s0v);
      }
      *(unsigned*)&tps[el * LDK + 64 + sub * 2] = *(unsigned*)ts2;
#pragma unroll
      for (int c = 0; c < 3; c++)
        *(unsigned*)&tpv[(el * 3 + c) * LDK + 64 + sub * 2] = *(unsigned*)tv2[c];
    }
    __syncthreads();
    // ---- phase C: all 24 MFMA tiles (12 G1 + 12 G2), 3 per wave ----
    float4v acc2[3];
#pragma unroll
    for (int tt = 0; tt < 3; tt++) {
      const int id = wave + tt * 8;
      float4v acc = {0.f, 0.f, 0.f, 0.f};
      if (id < 12) {
        // GEMM1 tile: m_s[32][96]
        const int mt = id / 6, nt = id % 6;
#pragma unroll
        for (int kk = 0; kk < 3; kk++) {
          short8 a = *(const short8*)&tps[(mt * 16 + lm) * LDK + kk * 32 + quad * 8];
          short8 b = *(const short8*)&w2sT[(nt * 16 + lm) * LDK + kk * 32 + quad * 8];
          acc = __builtin_amdgcn_mfma_f32_16x16x32_bf16(a, b, acc, 0, 0, 0);
        }
        const int j = nt * 16 + lm;
#pragma unroll
        for (int reg = 0; reg < 4; reg++) {
          const int e = mt * 16 + quad * 4 + reg;
          const float val = acc[reg];
          if (j < 64) {
            if (STORE) msgS[(size_t)(ebase + e) * 64 + j] = f2bf(silu_f(val));
            else atomicAdd(&aggs[(size_t)sdst[e] * 64 + j], silu_f(val));
          } else {
            gat[e][j - 64] = sigm_f(val);
          }
        }
      } else {
        // GEMM2 tile: m_v[96][32], gate applied after sync
        const int id2 = id - 12;
        const int mt = id2 >> 1, nt2 = id2 & 1;
#pragma unroll
        for (int kk = 0; kk < 3; kk++) {
          short8 a = *(const short8*)&tpv[(mt * 16 + lm) * LDK + kk * 32 + quad * 8];
          short8 b = *(const short8*)&w2vT[(nt2 * 16 + lm) * LDK + kk * 32 + quad * 8];
          acc = __builtin_amdgcn_mfma_f32_16x16x32_bf16(a, b, acc, 0, 0, 0);
        }
        acc2[tt] = acc;
      }
    }
    __syncthreads();
    // ---- phase D: gate + store m_v ----
#pragma unroll
    for (int tt = 0; tt < 3; tt++) {
      const int id = wave + tt * 8;
      if (id >= 12) {
        const int id2 = id - 12;
        const int mt = id2 >> 1, nt2 = id2 & 1;
        const int v = nt2 * 16 + lm;
#pragma unroll
        for (int reg = 0; reg < 4; reg++) {
          const int r = mt * 16 + quad * 4 + reg;
          const int e = (r * 171) >> 9, c = r - 3 * e;
          const float val = acc2[tt][reg] * gat[e][v];
          if (STORE) msgV[(size_t)(ebase + e) * 96 + v * 3 + c] = f2bf(val);
          else atomicAdd(&aggv[(size_t)sdst[e] * 96 + v * 3 + c], val);
        }
      }
    }
  }
}

// ---------------- Kernel B2: wave-per-node gather-reduction via perm ----------------
__global__ __launch_bounds__(256, 8)
void k_agg(const unsigned short* __restrict__ msgS, const unsigned short* __restrict__ msgV,
           const int* __restrict__ rowp, const int* __restrict__ perm,
           float* __restrict__ aggs, float* __restrict__ aggv) {
  const int wv = threadIdx.x >> 6, lane = threadIdx.x & 63;
  const int n = blockIdx.x * 4 + wv;
  const int lo = rowp[n], hi = rowp[n + 1];
  float sS = 0.f, v0 = 0.f, v1a = 0.f;
  int r = lo;
  for (; r + 2 <= hi; r += 2) {
    const int e0 = perm[r], e1 = perm[r + 1];
    const unsigned short a0 = msgS[(size_t)e0 * 64 + lane];
    const unsigned short a1 = msgS[(size_t)e1 * 64 + lane];
    const unsigned short b0 = msgV[(size_t)e0 * 96 + lane];
    const unsigned short b1 = msgV[(size_t)e1 * 96 + lane];
    unsigned short c0 = 0, c1 = 0;
    if (lane < 32) {
      c0 = msgV[(size_t)e0 * 96 + 64 + lane];
      c1 = msgV[(size_t)e1 * 96 + 64 + lane];
    }
    sS += bf2f(a0) + bf2f(a1);
    v0 += bf2f(b0) + bf2f(b1);
    v1a += bf2f(c0) + bf2f(c1);
  }
  for (; r < hi; r++) {
    const int e0 = perm[r];
    sS += bf2f(msgS[(size_t)e0 * 64 + lane]);
    v0 += bf2f(msgV[(size_t)e0 * 96 + lane]);
    if (lane < 32) v1a += bf2f(msgV[(size_t)e0 * 96 + 64 + lane]);
  }
  aggs[(size_t)n * 64 + lane] = sS;
  aggv[(size_t)n * 96 + lane] = v0;
  if (lane < 32) aggv[(size_t)n * 96 + 64 + lane] = v1a;
}

// ---------------- Kernel C1: MFMA GEMM  [32 nodes x 1088] @ BT^T -> 96 cols ----------------
__global__ __launch_bounds__(256, 4)
void k_c1(const float* __restrict__ node_s, const float* __restrict__ attrs,
          const float* __restrict__ aggs, const float* __restrict__ Wt0,
          const unsigned short* __restrict__ BT,
          float* __restrict__ out, float* __restrict__ gates) {
  __shared__ float s_row[32][64];
  __shared__ float attr[32][16];
  __shared__ float t0[32][64];
  __shared__ float wt0[1024];
  __shared__ unsigned short As[32 * 72];
  const int t = threadIdx.x;
  const int wave = t >> 6, lane = t & 63, lm = lane & 15, quad = lane >> 4;
  const int nbase = blockIdx.x * 32;

  for (int i = t; i < 1024; i += 256) wt0[i] = Wt0[i];
  for (int i = t; i < 2048; i += 256) {
    int nl = i >> 6, u = i & 63, n = nbase + nl;
    s_row[nl][u] = (n < N) ? node_s[(size_t)n * 64 + u] : 0.f;
    t0[nl][u]    = (n < N) ? aggs[(size_t)n * 64 + u] : 0.f;
  }
  for (int i = t; i < 512; i += 256) {
    int nl = i >> 4, a = i & 15, n = nbase + nl;
    attr[nl][a] = (n < N) ? attrs[(size_t)n * 16 + a] : 0.f;
  }
  __syncthreads();
  for (int i = t; i < 2048; i += 256) {
    int nl = i >> 6, u = i & 63;
    float d0 = 0.f;
#pragma unroll
    for (int a = 0; a < 16; a++) d0 += attr[nl][a] * wt0[u * 16 + a];
    t0[nl][u] *= d0 * 0.07216878364870322f;   // 1/(sqrt(16)*sqrt(12))
  }

  float4v acc[3] = {{0,0,0,0},{0,0,0,0},{0,0,0,0}};
  int mts[3], nts[3];
#pragma unroll
  for (int tt = 0; tt < 3; tt++) {
    const int tile = wave + tt * 4;    // 0..11 = mt*6+nt
    mts[tt] = tile / 6;
    nts[tt] = tile % 6;
  }

  for (int kc = 0; kc < 17; kc++) {
    __syncthreads();
    {
      const int row = t >> 3, c0 = (t & 7) * 8;
      unsigned short tmp[8];
      if (kc < 16) {
        const int u = kc * 4 + (c0 >> 4);
        const float sval = s_row[row][u];
        const int ab = c0 & 8;
#pragma unroll
        for (int i = 0; i < 8; i++) tmp[i] = f2bf(sval * attr[row][ab + i]);
      } else {
#pragma unroll
        for (int i = 0; i < 8; i++) tmp[i] = f2bf(t0[row][c0 + i]);
      }
      *(uint4*)&As[row * 72 + c0] = *(uint4*)tmp;
    }
    __syncthreads();
#pragma unroll
    for (int ks = 0; ks < 2; ks++) {
      short8 am0 = *(const short8*)&As[(lm) * 72 + ks * 32 + quad * 8];
      short8 am1 = *(const short8*)&As[(16 + lm) * 72 + ks * 32 + quad * 8];
#pragma unroll
      for (int tt = 0; tt < 3; tt++) {
        short8 b = *(const short8*)&BT[(size_t)(nts[tt] * 16 + lm) * 1088 + kc * 64 + ks * 32 + quad * 8];
        acc[tt] = __builtin_amdgcn_mfma_f32_16x16x32_bf16(mts[tt] ? am1 : am0, b, acc[tt], 0, 0, 0);
      }
    }
  }
#pragma unroll
  for (int tt = 0; tt < 3; tt++) {
    const int j = nts[tt] * 16 + lm;
#pragma unroll
    for (int reg = 0; reg < 4; reg++) {
      const int m = mts[tt] * 16 + quad * 4 + reg;
      const int n = nbase + m;
      if (n < N) {
        const float val = acc[tt][reg];
        if (j < 64) out[(size_t)n * 160 + j] = silu_f(val);
        else        gates[(size_t)n * 32 + (j - 64)] = sigm_f(val);
      }
    }
  }
}

// ---------------- Kernel C2: MFMA GEMM  [96 rows (32n x 3c) x 544] @ B2T^T -> 32 cols ----------------
__global__ __launch_bounds__(256, 3)
void k_c2(const float* __restrict__ node_v, const float* __restrict__ attrs,
          const float* __restrict__ aggv, const float* __restrict__ Wt1,
          const unsigned short* __restrict__ B2T, const float* __restrict__ gts,
          float* __restrict__ out) {
  __shared__ float nvs[32][96];
  __shared__ float t1s[32][96];
  __shared__ float attr[32][16];
  __shared__ float wt1[512];
  __shared__ unsigned short As2[96 * 72];
  const int t = threadIdx.x;
  const int wave = t >> 6, lane = t & 63, lm = lane & 15, quad = lane >> 4;
  const int nbase = blockIdx.x * 32;

  for (int i = t; i < 512; i += 256) wt1[i] = Wt1[i];
  for (int i = t; i < 32 * 96; i += 256) {
    int nl = i / 96, rr = i % 96, n = nbase + nl;
    nvs[nl][rr] = (n < N) ? node_v[(size_t)n * 96 + rr] : 0.f;
    t1s[nl][rr] = (n < N) ? aggv[(size_t)n * 96 + rr] : 0.f;
  }
  for (int i = t; i < 512; i += 256) {
    int nl = i >> 4, a = i & 15, n = nbase + nl;
    attr[nl][a] = (n < N) ? attrs[(size_t)n * 16 + a] : 0.f;
  }
  __syncthreads();
  for (int i = t; i < 1024; i += 256) {
    int nl = i >> 5, u = i & 31;
    float d1 = 0.f;
#pragma unroll
    for (int a = 0; a < 16; a++) d1 += attr[nl][a] * wt1[u * 16 + a];
    d1 *= 0.07216878364870322f;
    t1s[nl][u * 3 + 0] *= d1; t1s[nl][u * 3 + 1] *= d1; t1s[nl][u * 3 + 2] *= d1;
  }

  float4v acc[3] = {{0,0,0,0},{0,0,0,0},{0,0,0,0}};
  int mts[3], nts[3];
#pragma unroll
  for (int tt = 0; tt < 3; tt++) {
    const int tile = wave + tt * 4;   // 0..11 = mt*2+nt
    mts[tt] = tile >> 1;
    nts[tt] = tile & 1;
  }

  for (int kc = 0; kc < 9; kc++) {
    __syncthreads();
#pragma unroll
    for (int jj = 0; jj < 3; jj++) {
      const int job = t + jj * 256;
      const int row = job >> 3, c0 = (job & 7) * 8;
      const int nl = (row * 171) >> 9, c = row - 3 * nl;
      const int kbase = kc * 64 + c0;
      unsigned short tmp[8];
      if (kbase < 512) {
        const int u = kbase >> 4;
        const float vval = nvs[nl][u * 3 + c];
        const int ab = c0 & 8;
#pragma unroll
        for (int i = 0; i < 8; i++) tmp[i] = f2bf(vval * attr[nl][ab + i]);
      } else if (kbase < 544) {
        const int u2 = kbase - 512;
#pragma unroll
        for (int i = 0; i < 8; i++) tmp[i] = f2bf(t1s[nl][(u2 + i) * 3 + c]);
      } else {
#pragma unroll
        for (int i = 0; i < 8; i++) tmp[i] = 0;
      }
      *(uint4*)&As2[row * 72 + c0] = *(uint4*)tmp;
    }
    __syncthreads();
#pragma unroll
    for (int ks = 0; ks < 2; ks++) {
#pragma unroll
      for (int tt = 0; tt < 3; tt++) {
        short8 a = *(const short8*)&As2[(mts[tt] * 16 + lm) * 72 + ks * 32 + quad * 8];
        short8 b = *(const short8*)&B2T[(size_t)(nts[tt] * 16 + lm) * 576 + kc * 64 + ks * 32 + quad * 8];
        acc[tt] = __builtin_amdgcn_mfma_f32_16x16x32_bf16(a, b, acc[tt], 0, 0, 0);
      }
    }
  }
#pragma unroll
  for (int tt = 0; tt < 3; tt++) {
    const int w = nts[tt] * 16 + lm;
#pragma unroll
    for (int reg = 0; reg < 4; reg++) {
      const int row = mts[tt] * 16 + quad * 4 + reg;
      const int nl = (row * 171) >> 9, c = row - 3 * nl;
      const int n = nbase + nl;
      if (n < N)
        out[(size_t)n * 160 + 64 + w * 3 + c] = acc[tt][reg] * gts[(size_t)n * 32 + w];
    }
  }
}

extern "C" void kernel_launch(void* const* d_in, const int* in_sizes, int n_in,
                              void* d_out, int out_size, void* d_ws, size_t ws_size,
                              hipStream_t stream) {
  const float* node_s = (const float*)d_in[0];
  const float* node_v = (const float*)d_in[1];
  const float* attrs  = (const float*)d_in[2];
  const float* emb    = (const float*)d_in[3];
  const float* sh0    = (const float*)d_in[4];
  const float* sh1    = (const float*)d_in[5];
  const int*   eidx   = (const int*)d_in[6];
  const float* W1s    = (const float*)d_in[7];
  const float* W1v    = (const float*)d_in[8];
  const float* Wm1    = (const float*)d_in[9];
  const float* Wm2    = (const float*)d_in[10];
  const float* W2s    = (const float*)d_in[11];
  const float* W2v    = (const float*)d_in[12];
  const float* Wt0    = (const float*)d_in[13];
  const float* Wt1    = (const float*)d_in[14];
  const float* W3s    = (const float*)d_in[15];
  const float* W3v    = (const float*)d_in[16];
  const float* Wsc0   = (const float*)d_in[17];
  const float* Wsc1   = (const float*)d_in[18];

  char* p = (char*)d_ws;
  float* s1  = (float*)p;  p += (size_t)N * 64 * 4;
  float* v1f = (float*)p;  p += (size_t)N * 96 * 4;
  float* gts = (float*)p;  p += (size_t)N * 32 * 4;
  unsigned short* BT  = (unsigned short*)p;  p += (size_t)96 * 1088 * 2;
  unsigned short* B2T = (unsigned short*)p;  p += (size_t)32 * 576 * 2;
  char* pmode = p;
  size_t base = (size_t)(pmode - (char*)d_ws);
  size_t need_store = base + ((size_t)N + 1) * 4 + (size_t)N * 4 + (size_t)E * 4
                    + (size_t)E * 64 * 2 + (size_t)E * 96 * 2;
  const bool store = (ws_size >= need_store);

  k_prep<<<480, 256, 0, stream>>>(Wsc0, W3s, Wsc1, W3v, BT, B2T);
  k_lin1<<<1024, 256, 0, stream>>>(node_s, node_v, W1s, W1v, s1, v1f);

  if (store) {
    int* rowp = (int*)pmode;
    int* cnt  = rowp + (N + 1);
    int* perm = cnt + N;
    unsigned short* msgS = (unsigned short*)(perm + E);
    unsigned short* msgV = msgS + (size_t)E * 64;
    hipMemsetAsync(cnt, 0, (size_t)N * 4, stream);
    k_hist<<<(E + 255) / 256, 256, 0, stream>>>(eidx, cnt);
    k_scan<<<1, 1024, 0, stream>>>(cnt, rowp);
    hipMemsetAsync(cnt, 0, (size_t)N * 4, stream);
    k_scatter<<<(E + 255) / 256, 256, 0, stream>>>(eidx, rowp, cnt, perm);
    k_msg<1><<<512, 512, 0, stream>>>(s1, v1f, emb, sh0, sh1, eidx, Wm1, Wm2, W2s, W2v,
                                      nullptr, nullptr, msgS, msgV);
    float* aggs = s1;    // s1/v1 dead after k_msg: alias
    float* aggv = v1f;
    k_agg<<<N / 4, 256, 0, stream>>>(msgS, msgV, rowp, perm, aggs, aggv);
    k_c1<<<1563, 256, 0, stream>>>(node_s, attrs, aggs, Wt0, BT, (float*)d_out, gts);
    k_c2<<<1563, 256, 0, stream>>>(node_v, attrs, aggv, Wt1, B2T, gts, (float*)d_out);
  } else {
    float* aggs = (float*)pmode;
    float* aggv = aggs + (size_t)N * 64;
    hipMemsetAsync(aggs, 0, (size_t)N * 160 * 4, stream);
    k_msg<0><<<512, 512, 0, stream>>>(s1, v1f, emb, sh0, sh1, eidx, Wm1, Wm2, W2s, W2v,
                                      aggs, aggv, nullptr, nullptr);
    k_c1<<<1563, 256, 0, stream>>>(node_s, attrs, aggs, Wt0, BT, (float*)d_out, gts);
    k_c2<<<1563, 256, 0, stream>>>(node_v, attrs, aggv, Wt1, B2T, gts, (float*)d_out);
  }
}

// Round 3
// 928.762 us; speedup vs baseline: 1.3198x; 1.2499x over previous
//
#include <hip/hip_runtime.h>
#include <math.h>

#define N 50000
#define E 600000
#define EPB 16     // edges per pass
#define LDK 104    // padded K stride (bf16 elems) for tp tiles

typedef __attribute__((ext_vector_type(8))) short short8;
typedef __attribute__((ext_vector_type(4))) float float4v;

__device__ __forceinline__ float silu_f(float x) { return x / (1.f + __expf(-x)); }
__device__ __forceinline__ float sigm_f(float x) { return 1.f / (1.f + __expf(-x)); }
__device__ __forceinline__ unsigned short f2bf(float f) {
  unsigned u = __float_as_uint(f);
  u += 0x7fff + ((u >> 16) & 1);   // RNE
  return (unsigned short)(u >> 16);
}
__device__ __forceinline__ float bf2f(unsigned short u) {
  return __uint_as_float(((unsigned)u) << 16);
}

// ---------------- CSR build ----------------
__global__ void k_hist(const int* __restrict__ eidx, int* __restrict__ counts) {
  int e = blockIdx.x * 256 + threadIdx.x;
  if (e < E) atomicAdd(&counts[eidx[E + e]], 1);
}

__global__ __launch_bounds__(1024)
void k_scan(const int* __restrict__ counts, int* __restrict__ row_ptr) {
  __shared__ int ssum[1024];
  const int t = threadIdx.x;
  const int CH = 49;
  int lo = t * CH, hi = min(lo + CH, N);
  int s = 0;
  for (int i = lo; i < hi; i++) s += counts[i];
  ssum[t] = s;
  __syncthreads();
  for (int off = 1; off < 1024; off <<= 1) {
    int v = (t >= off) ? ssum[t - off] : 0;
    __syncthreads();
    ssum[t] += v;
    __syncthreads();
  }
  int run = (t == 0) ? 0 : ssum[t - 1];
  for (int i = lo; i < hi; i++) { row_ptr[i] = run; run += counts[i]; }
  if (t == 1023) row_ptr[N] = ssum[1023];
}

__global__ void k_scatter(const int* __restrict__ eidx, const int* __restrict__ row_ptr,
                          int* __restrict__ woff, int* __restrict__ perm) {
  int e = blockIdx.x * 256 + threadIdx.x;
  if (e < E) {
    int d = eidx[E + e];
    int p = atomicAdd(&woff[d], 1);
    perm[row_ptr[d] + p] = e;
  }
}

// ---------------- weight prep: bf16 transposed B matrices ----------------
// Adds w2sTg [96][96] and w2vTg [32][96] (isq96 folded): k_msg reads its MFMA
// B-operands directly from these (24KB total -> L1-resident), freeing 26.6KB LDS.
__global__ void k_prep(const float* __restrict__ Wsc0, const float* __restrict__ W3s,
                       const float* __restrict__ Wsc1, const float* __restrict__ W3v,
                       const float* __restrict__ W2s, const float* __restrict__ W2v,
                       unsigned short* __restrict__ BT, unsigned short* __restrict__ B2T,
                       unsigned short* __restrict__ w2sTg, unsigned short* __restrict__ w2vTg) {
  const float isq96 = 0.10206207261596575f;
  int i = blockIdx.x * 256 + threadIdx.x;
  if (i < 96 * 1088) {
    int j = i / 1088, k = i % 1088;
    float v;
    if (k < 1024) v = Wsc0[(size_t)k * 96 + j] * 0.03125f;          // 1/sqrt(1024)
    else          v = W3s[(size_t)(k - 1024) * 96 + j] * 0.125f;    // 1/sqrt(64)
    BT[i] = f2bf(v);
  } else if (i < 96 * 1088 + 32 * 576) {
    int i2 = i - 96 * 1088;
    int w = i2 / 576, k = i2 % 576;
    float v = 0.f;
    if (k < 512)      v = Wsc1[(size_t)k * 32 + w] * 0.04419417382415922f;  // 1/sqrt(512)
    else if (k < 544) v = W3v[(size_t)(k - 512) * 32 + w] * 0.17677669529663689f; // 1/sqrt(32)
    B2T[i2] = f2bf(v);
  } else if (i < 96 * 1088 + 32 * 576 + 96 * 96) {
    int i3 = i - (96 * 1088 + 32 * 576);
    int j = i3 / 96, k = i3 % 96;            // w2sTg[j][k] = W2s[k][j]
    w2sTg[i3] = f2bf(W2s[(size_t)k * 96 + j] * isq96);
  } else {
    int i4 = i - (96 * 1088 + 32 * 576 + 96 * 96);
    if (i4 < 32 * 96) {
      int v = i4 / 96, u = i4 % 96;          // w2vTg[v][u] = W2v[u][v]
      w2vTg[i4] = f2bf(W2v[(size_t)u * 32 + v] * isq96);
    }
  }
}

// ---------------- Kernel A: s1 = node_s@W1s/8 ; v1 = node_v x W1v /sqrt(32) ----------------
__global__ __launch_bounds__(256, 4)
void k_lin1(const float* __restrict__ node_s, const float* __restrict__ node_v,
            const float* __restrict__ W1s, const float* __restrict__ W1v,
            float* __restrict__ s1, float* __restrict__ v1) {
  __shared__ float w1s[64 * 64];
  __shared__ float w1v[32 * 32];
  for (int i = threadIdx.x; i < 64 * 64; i += 256) w1s[i] = W1s[i];
  for (int i = threadIdx.x; i < 32 * 32; i += 256) w1v[i] = W1v[i];
  __syncthreads();
  const float is_ns = 0.125f;
  const float is_nv = 0.17677669529663689f;
  int gtid = blockIdx.x * 256 + threadIdx.x;
  int stride = gridDim.x * 256;
  for (int i = gtid; i < N * 160; i += stride) {
    int n = i / 160, ch = i % 160;
    if (ch < 64) {
      const float* row = node_s + n * 64;
      float acc = 0.f;
#pragma unroll
      for (int u = 0; u < 64; u++) acc += row[u] * w1s[u * 64 + ch];
      s1[n * 64 + ch] = acc * is_ns;
    } else {
      int p = ch - 64, v = p / 3, c = p % 3;
      const float* row = node_v + n * 96;
      float acc = 0.f;
#pragma unroll
      for (int u = 0; u < 32; u++) acc += row[u * 3 + c] * w1v[u * 32 + v];
      v1[n * 96 + p] = acc * is_nv;
    }
  }
}

// ---------------- Kernel B: streaming per-edge message via MFMA ----------------
// R0-proven structure (EPB=16, 256 threads). Change vs R0: B matrices
// (w2sTg/w2vTg, 24KB bf16) are read directly from global (L1-resident),
// and the Wm2 register-cache loads straight from global -- LDS drops
// 50,176 -> 16,640 B, lifting the 3-blocks/CU occupancy cap.
// STORE=1: coalesced bf16 messages in edge order (k_agg gathers via perm)
// STORE=0: fallback, atomicAdd into aggs/aggv
template<int STORE>
__global__ __launch_bounds__(256, 3)
void k_msg(const float* __restrict__ s1, const float* __restrict__ v1,
           const float* __restrict__ emb, const float* __restrict__ sh0g,
           const float* __restrict__ sh1g, const int* __restrict__ eidx,
           const float* __restrict__ Wm1, const float* __restrict__ Wm2,
           const unsigned short* __restrict__ w2sTg, const unsigned short* __restrict__ w2vTg,
           float* __restrict__ aggs, float* __restrict__ aggv,
           unsigned short* __restrict__ msgS, unsigned short* __restrict__ msgV) {
  __shared__ float wm1s[64];
  __shared__ unsigned short tps[EPB * LDK];
  __shared__ unsigned short tpv[EPB * 3 * LDK];
  __shared__ float gat[EPB][33];              // padded: bank-conflict-free
  __shared__ float hb[EPB][8];
  __shared__ float sh1b[EPB][4];
  __shared__ float sh0b[EPB];
  __shared__ int ssrc[EPB];
  __shared__ int sdst[EPB];

  const int t = threadIdx.x;
  const int wave = t >> 6, lane = t & 63;
  const int lm = lane & 15, quad = lane >> 4;

  if (t < 64) wm1s[t] = Wm1[t];
  // register-cache this thread's 12 Wm2 rows directly from global (6KB, L2-hot)
  const int subc = t & 15;
  float wA0[4][8], wA1[4][8], wB1[2][8], wB0[2][8];
#pragma unroll
  for (int i = 0; i < 4; i++)
#pragma unroll
    for (int h = 0; h < 8; h++) {
      wA0[i][h] = Wm2[h * 192 + (subc * 4 + i)];
      wA1[i][h] = Wm2[h * 192 + (64 + subc * 4 + i)];
    }
#pragma unroll
  for (int i2 = 0; i2 < 2; i2++)
#pragma unroll
    for (int h = 0; h < 8; h++) {
      wB1[i2][h] = Wm2[h * 192 + (128 + subc * 2 + i2)];
      wB0[i2][h] = Wm2[h * 192 + (160 + subc * 2 + i2)];
    }
  __syncthreads();

  for (int pass = blockIdx.x; pass < E / EPB; pass += gridDim.x) {
    const int ebase = pass * EPB;
    __syncthreads();
    // ---- phase A: stage edge meta + radial MLP hidden (disjoint threads) ----
    if (t < EPB) {
      ssrc[t] = eidx[ebase + t];
      if (!STORE) sdst[t] = eidx[E + ebase + t];
      sh0b[t] = sh0g[ebase + t];
    } else if (t >= 64 && t < 64 + EPB * 3) {
      int i = t - 64;
      sh1b[i / 3][i % 3] = sh1g[ebase * 3 + i];
    } else if (t >= 128) {
      int i = t - 128, el = i >> 3, sub = i & 7;
      float acc = 0.f;
#pragma unroll
      for (int r = 0; r < 8; r++) acc += emb[(ebase + el) * 8 + r] * wm1s[r * 8 + sub];
      hb[el][sub] = silu_f(acc);
    }
    __syncthreads();
    // ---- phase B: build TPS / TPV (bf16), weights all in registers ----
    {
      const int el = t >> 4, sub = subc;
      const int src = ssrc[el];
      const float s0v = sh0b[el];
      const float x0 = sh1b[el][0], x1 = sh1b[el][1], x2 = sh1b[el][2];
      float hr[8];
#pragma unroll
      for (int h = 0; h < 8; h++) hr[h] = hb[el][h];
      const float4v ss = *(const float4v*)&s1[(size_t)src * 64 + sub * 4];
      unsigned short tsv[4], tvv[3][4];
#pragma unroll
      for (int i = 0; i < 4; i++) {
        float w0a = 0.f, w1a = 0.f;
#pragma unroll
        for (int h = 0; h < 8; h++) {
          w0a += hr[h] * wA0[i][h];
          w1a += hr[h] * wA1[i][h];
        }
        const float ssu = ss[i];
        tsv[i] = f2bf(w0a * ssu * s0v);
        const float base = w1a * ssu;
        tvv[0][i] = f2bf(base * x0);
        tvv[1][i] = f2bf(base * x1);
        tvv[2][i] = f2bf(base * x2);
      }
      *(uint2*)&tps[el * LDK + sub * 4] = *(uint2*)tsv;
#pragma unroll
      for (int c = 0; c < 3; c++)
        *(uint2*)&tpv[(el * 3 + c) * LDK + sub * 4] = *(uint2*)tvv[c];
      const float2* vp = (const float2*)&v1[(size_t)src * 96 + sub * 6];
      const float2 va = vp[0], vb = vp[1], vc = vp[2];
      const float v6[6] = {va.x, va.y, vb.x, vb.y, vc.x, vc.y};
      unsigned short ts2[2], tv2[3][2];
#pragma unroll
      for (int i2 = 0; i2 < 2; i2++) {
        float w1b = 0.f, w0b = 0.f;
#pragma unroll
        for (int h = 0; h < 8; h++) {
          w1b += hr[h] * wB1[i2][h];
          w0b += hr[h] * wB0[i2][h];
        }
        const float vx = v6[i2 * 3 + 0], vy = v6[i2 * 3 + 1], vz = v6[i2 * 3 + 2];
        ts2[i2] = f2bf(w0b * (vx * x0 + vy * x1 + vz * x2));
        tv2[0][i2] = f2bf(w1b * vx * s0v);
        tv2[1][i2] = f2bf(w1b * vy * s0v);
        tv2[2][i2] = f2bf(w1b * vz * s0v);
      }
      *(unsigned*)&tps[el * LDK + 64 + sub * 2] = *(unsigned*)ts2;
#pragma unroll
      for (int c = 0; c < 3; c++)
        *(unsigned*)&tpv[(el * 3 + c) * LDK + 64 + sub * 2] = *(unsigned*)tv2[c];
    }
    __syncthreads();
    // ---- GEMM1: m_s[16][96] (B operand from global, L1-hot) ----
    {
      short8 afr[3];
#pragma unroll
      for (int kk = 0; kk < 3; kk++)
        afr[kk] = *(const short8*)&tps[lm * LDK + kk * 32 + quad * 8];
#pragma unroll
      for (int t2 = 0; t2 < 2; t2++) {
        const int nt = wave + t2 * 4;
        if (nt < 6) {
          float4v acc = {0.f, 0.f, 0.f, 0.f};
#pragma unroll
          for (int kk = 0; kk < 3; kk++) {
            short8 bfr = *(const short8*)&w2sTg[(nt * 16 + lm) * 96 + kk * 32 + quad * 8];
            acc = __builtin_amdgcn_mfma_f32_16x16x32_bf16(afr[kk], bfr, acc, 0, 0, 0);
          }
          const int j = nt * 16 + lm;
#pragma unroll
          for (int reg = 0; reg < 4; reg++) {
            const int e = quad * 4 + reg;
            const float val = acc[reg];
            if (j < 64) {
              if (STORE) msgS[(size_t)(ebase + e) * 64 + j] = f2bf(silu_f(val));
              else atomicAdd(&aggs[(size_t)sdst[e] * 64 + j], silu_f(val));
            } else {
              gat[e][j - 64] = sigm_f(val);
            }
          }
        }
      }
    }
    __syncthreads();
    // ---- GEMM2: m_v[48][32] ----
#pragma unroll
    for (int t2 = 0; t2 < 2; t2++) {
      const int tile = wave + t2 * 4;
      if (tile < 6) {
        const int mt = tile >> 1, nt2 = tile & 1;
        float4v acc = {0.f, 0.f, 0.f, 0.f};
#pragma unroll
        for (int kk = 0; kk < 3; kk++) {
          short8 a = *(const short8*)&tpv[(mt * 16 + lm) * LDK + kk * 32 + quad * 8];
          short8 b = *(const short8*)&w2vTg[(nt2 * 16 + lm) * 96 + kk * 32 + quad * 8];
          acc = __builtin_amdgcn_mfma_f32_16x16x32_bf16(a, b, acc, 0, 0, 0);
        }
        const int v = nt2 * 16 + lm;
#pragma unroll
        for (int reg = 0; reg < 4; reg++) {
          const int r = mt * 16 + quad * 4 + reg;
          const int e = (r * 171) >> 9, c = r - 3 * e;
          const float val = acc[reg] * gat[e][v];
          if (STORE) msgV[(size_t)(ebase + e) * 96 + v * 3 + c] = f2bf(val);
          else atomicAdd(&aggv[(size_t)sdst[e] * 96 + v * 3 + c], val);
        }
      }
    }
  }
}

// ---------------- Kernel B2: wave-per-node gather-reduction via perm ----------------
__global__ __launch_bounds__(256, 8)
void k_agg(const unsigned short* __restrict__ msgS, const unsigned short* __restrict__ msgV,
           const int* __restrict__ rowp, const int* __restrict__ perm,
           float* __restrict__ aggs, float* __restrict__ aggv) {
  const int wv = threadIdx.x >> 6, lane = threadIdx.x & 63;
  const int n = blockIdx.x * 4 + wv;
  const int lo = rowp[n], hi = rowp[n + 1];
  float sS = 0.f, v0 = 0.f, v1a = 0.f;
  int r = lo;
  for (; r + 2 <= hi; r += 2) {
    const int e0 = perm[r], e1 = perm[r + 1];
    const unsigned short a0 = msgS[(size_t)e0 * 64 + lane];
    const unsigned short a1 = msgS[(size_t)e1 * 64 + lane];
    const unsigned short b0 = msgV[(size_t)e0 * 96 + lane];
    const unsigned short b1 = msgV[(size_t)e1 * 96 + lane];
    unsigned short c0 = 0, c1 = 0;
    if (lane < 32) {
      c0 = msgV[(size_t)e0 * 96 + 64 + lane];
      c1 = msgV[(size_t)e1 * 96 + 64 + lane];
    }
    sS += bf2f(a0) + bf2f(a1);
    v0 += bf2f(b0) + bf2f(b1);
    v1a += bf2f(c0) + bf2f(c1);
  }
  for (; r < hi; r++) {
    const int e0 = perm[r];
    sS += bf2f(msgS[(size_t)e0 * 64 + lane]);
    v0 += bf2f(msgV[(size_t)e0 * 96 + lane]);
    if (lane < 32) v1a += bf2f(msgV[(size_t)e0 * 96 + 64 + lane]);
  }
  aggs[(size_t)n * 64 + lane] = sS;
  aggv[(size_t)n * 96 + lane] = v0;
  if (lane < 32) aggv[(size_t)n * 96 + 64 + lane] = v1a;
}

// ---------------- Kernel C1: MFMA GEMM  [32 nodes x 1088] @ BT^T -> 96 cols ----------------
__global__ __launch_bounds__(256, 4)
void k_c1(const float* __restrict__ node_s, const float* __restrict__ attrs,
          const float* __restrict__ aggs, const float* __restrict__ Wt0,
          const unsigned short* __restrict__ BT,
          float* __restrict__ out, float* __restrict__ gates) {
  __shared__ float s_row[32][64];
  __shared__ float attr[32][16];
  __shared__ float t0[32][64];
  __shared__ float wt0[1024];
  __shared__ unsigned short As[32 * 72];
  const int t = threadIdx.x;
  const int wave = t >> 6, lane = t & 63, lm = lane & 15, quad = lane >> 4;
  const int nbase = blockIdx.x * 32;

  for (int i = t; i < 1024; i += 256) wt0[i] = Wt0[i];
  for (int i = t; i < 2048; i += 256) {
    int nl = i >> 6, u = i & 63, n = nbase + nl;
    s_row[nl][u] = (n < N) ? node_s[(size_t)n * 64 + u] : 0.f;
    t0[nl][u]    = (n < N) ? aggs[(size_t)n * 64 + u] : 0.f;
  }
  for (int i = t; i < 512; i += 256) {
    int nl = i >> 4, a = i & 15, n = nbase + nl;
    attr[nl][a] = (n < N) ? attrs[(size_t)n * 16 + a] : 0.f;
  }
  __syncthreads();
  for (int i = t; i < 2048; i += 256) {
    int nl = i >> 6, u = i & 63;
    float d0 = 0.f;
#pragma unroll
    for (int a = 0; a < 16; a++) d0 += attr[nl][a] * wt0[u * 16 + a];
    t0[nl][u] *= d0 * 0.07216878364870322f;   // 1/(sqrt(16)*sqrt(12))
  }

  float4v acc[3] = {{0,0,0,0},{0,0,0,0},{0,0,0,0}};
  int mts[3], nts[3];
#pragma unroll
  for (int tt = 0; tt < 3; tt++) {
    const int tile = wave + tt * 4;    // 0..11 = mt*6+nt
    mts[tt] = tile / 6;
    nts[tt] = tile % 6;
  }

  for (int kc = 0; kc < 17; kc++) {
    __syncthreads();
    {
      const int row = t >> 3, c0 = (t & 7) * 8;
      unsigned short tmp[8];
      if (kc < 16) {
        const int u = kc * 4 + (c0 >> 4);
        const float sval = s_row[row][u];
        const int ab = c0 & 8;
#pragma unroll
        for (int i = 0; i < 8; i++) tmp[i] = f2bf(sval * attr[row][ab + i]);
      } else {
#pragma unroll
        for (int i = 0; i < 8; i++) tmp[i] = f2bf(t0[row][c0 + i]);
      }
      *(uint4*)&As[row * 72 + c0] = *(uint4*)tmp;
    }
    __syncthreads();
#pragma unroll
    for (int ks = 0; ks < 2; ks++) {
      short8 am0 = *(const short8*)&As[(lm) * 72 + ks * 32 + quad * 8];
      short8 am1 = *(const short8*)&As[(16 + lm) * 72 + ks * 32 + quad * 8];
#pragma unroll
      for (int tt = 0; tt < 3; tt++) {
        short8 b = *(const short8*)&BT[(size_t)(nts[tt] * 16 + lm) * 1088 + kc * 64 + ks * 32 + quad * 8];
        acc[tt] = __builtin_amdgcn_mfma_f32_16x16x32_bf16(mts[tt] ? am1 : am0, b, acc[tt], 0, 0, 0);
      }
    }
  }
#pragma unroll
  for (int tt = 0; tt < 3; tt++) {
    const int j = nts[tt] * 16 + lm;
#pragma unroll
    for (int reg = 0; reg < 4; reg++) {
      const int m = mts[tt] * 16 + quad * 4 + reg;
      const int n = nbase + m;
      if (n < N) {
        const float val = acc[tt][reg];
        if (j < 64) out[(size_t)n * 160 + j] = silu_f(val);
        else        gates[(size_t)n * 32 + (j - 64)] = sigm_f(val);
      }
    }
  }
}

// ---------------- Kernel C2: MFMA GEMM  [96 rows (32n x 3c) x 544] @ B2T^T -> 32 cols ----------------
__global__ __launch_bounds__(256, 3)
void k_c2(const float* __restrict__ node_v, const float* __restrict__ attrs,
          const float* __restrict__ aggv, const float* __restrict__ Wt1,
          const unsigned short* __restrict__ B2T, const float* __restrict__ gts,
          float* __restrict__ out) {
  __shared__ float nvs[32][96];
  __shared__ float t1s[32][96];
  __shared__ float attr[32][16];
  __shared__ float wt1[512];
  __shared__ unsigned short As2[96 * 72];
  const int t = threadIdx.x;
  const int wave = t >> 6, lane = t & 63, lm = lane & 15, quad = lane >> 4;
  const int nbase = blockIdx.x * 32;

  for (int i = t; i < 512; i += 256) wt1[i] = Wt1[i];
  for (int i = t; i < 32 * 96; i += 256) {
    int nl = i / 96, rr = i % 96, n = nbase + nl;
    nvs[nl][rr] = (n < N) ? node_v[(size_t)n * 96 + rr] : 0.f;
    t1s[nl][rr] = (n < N) ? aggv[(size_t)n * 96 + rr] : 0.f;
  }
  for (int i = t; i < 512; i += 256) {
    int nl = i >> 4, a = i & 15, n = nbase + nl;
    attr[nl][a] = (n < N) ? attrs[(size_t)n * 16 + a] : 0.f;
  }
  __syncthreads();
  for (int i = t; i < 1024; i += 256) {
    int nl = i >> 5, u = i & 31;
    float d1 = 0.f;
#pragma unroll
    for (int a = 0; a < 16; a++) d1 += attr[nl][a] * wt1[u * 16 + a];
    d1 *= 0.07216878364870322f;
    t1s[nl][u * 3 + 0] *= d1; t1s[nl][u * 3 + 1] *= d1; t1s[nl][u * 3 + 2] *= d1;
  }

  float4v acc[3] = {{0,0,0,0},{0,0,0,0},{0,0,0,0}};
  int mts[3], nts[3];
#pragma unroll
  for (int tt = 0; tt < 3; tt++) {
    const int tile = wave + tt * 4;   // 0..11 = mt*2+nt
    mts[tt] = tile >> 1;
    nts[tt] = tile & 1;
  }

  for (int kc = 0; kc < 9; kc++) {
    __syncthreads();
#pragma unroll
    for (int jj = 0; jj < 3; jj++) {
      const int job = t + jj * 256;
      const int row = job >> 3, c0 = (job & 7) * 8;
      const int nl = (row * 171) >> 9, c = row - 3 * nl;
      const int kbase = kc * 64 + c0;
      unsigned short tmp[8];
      if (kbase < 512) {
        const int u = kbase >> 4;
        const float vval = nvs[nl][u * 3 + c];
        const int ab = c0 & 8;
#pragma unroll
        for (int i = 0; i < 8; i++) tmp[i] = f2bf(vval * attr[nl][ab + i]);
      } else if (kbase < 544) {
        const int u2 = kbase - 512;
#pragma unroll
        for (int i = 0; i < 8; i++) tmp[i] = f2bf(t1s[nl][(u2 + i) * 3 + c]);
      } else {
#pragma unroll
        for (int i = 0; i < 8; i++) tmp[i] = 0;
      }
      *(uint4*)&As2[row * 72 + c0] = *(uint4*)tmp;
    }
    __syncthreads();
#pragma unroll
    for (int ks = 0; ks < 2; ks++) {
#pragma unroll
      for (int tt = 0; tt < 3; tt++) {
        short8 a = *(const short8*)&As2[(mts[tt] * 16 + lm) * 72 + ks * 32 + quad * 8];
        short8 b = *(const short8*)&B2T[(size_t)(nts[tt] * 16 + lm) * 576 + kc * 64 + ks * 32 + quad * 8];
        acc[tt] = __builtin_amdgcn_mfma_f32_16x16x32_bf16(a, b, acc[tt], 0, 0, 0);
      }
    }
  }
#pragma unroll
  for (int tt = 0; tt < 3; tt++) {
    const int w = nts[tt] * 16 + lm;
#pragma unroll
    for (int reg = 0; reg < 4; reg++) {
      const int row = mts[tt] * 16 + quad * 4 + reg;
      const int nl = (row * 171) >> 9, c = row - 3 * nl;
      const int n = nbase + nl;
      if (n < N)
        out[(size_t)n * 160 + 64 + w * 3 + c] = acc[tt][reg] * gts[(size_t)n * 32 + w];
    }
  }
}

extern "C" void kernel_launch(void* const* d_in, const int* in_sizes, int n_in,
                              void* d_out, int out_size, void* d_ws, size_t ws_size,
                              hipStream_t stream) {
  const float* node_s = (const float*)d_in[0];
  const float* node_v = (const float*)d_in[1];
  const float* attrs  = (const float*)d_in[2];
  const float* emb    = (const float*)d_in[3];
  const float* sh0    = (const float*)d_in[4];
  const float* sh1    = (const float*)d_in[5];
  const int*   eidx   = (const int*)d_in[6];
  const float* W1s    = (const float*)d_in[7];
  const float* W1v    = (const float*)d_in[8];
  const float* Wm1    = (const float*)d_in[9];
  const float* Wm2    = (const float*)d_in[10];
  const float* W2s    = (const float*)d_in[11];
  const float* W2v    = (const float*)d_in[12];
  const float* Wt0    = (const float*)d_in[13];
  const float* Wt1    = (const float*)d_in[14];
  const float* W3s    = (const float*)d_in[15];
  const float* W3v    = (const float*)d_in[16];
  const float* Wsc0   = (const float*)d_in[17];
  const float* Wsc1   = (const float*)d_in[18];

  char* p = (char*)d_ws;
  float* s1  = (float*)p;  p += (size_t)N * 64 * 4;
  float* v1f = (float*)p;  p += (size_t)N * 96 * 4;
  float* gts = (float*)p;  p += (size_t)N * 32 * 4;
  unsigned short* BT    = (unsigned short*)p;  p += (size_t)96 * 1088 * 2;
  unsigned short* B2T   = (unsigned short*)p;  p += (size_t)32 * 576 * 2;
  unsigned short* w2sTg = (unsigned short*)p;  p += (size_t)96 * 96 * 2;
  unsigned short* w2vTg = (unsigned short*)p;  p += (size_t)32 * 96 * 2;
  char* pmode = p;
  size_t base = (size_t)(pmode - (char*)d_ws);
  size_t need_store = base + ((size_t)N + 1) * 4 + (size_t)N * 4 + (size_t)E * 4
                    + (size_t)E * 64 * 2 + (size_t)E * 96 * 2;
  const bool store = (ws_size >= need_store);

  k_prep<<<528, 256, 0, stream>>>(Wsc0, W3s, Wsc1, W3v, W2s, W2v, BT, B2T, w2sTg, w2vTg);
  k_lin1<<<1024, 256, 0, stream>>>(node_s, node_v, W1s, W1v, s1, v1f);

  if (store) {
    int* rowp = (int*)pmode;
    int* cnt  = rowp + (N + 1);
    int* perm = cnt + N;
    unsigned short* msgS = (unsigned short*)(perm + E);
    unsigned short* msgV = msgS + (size_t)E * 64;
    hipMemsetAsync(cnt, 0, (size_t)N * 4, stream);
    k_hist<<<(E + 255) / 256, 256, 0, stream>>>(eidx, cnt);
    k_scan<<<1, 1024, 0, stream>>>(cnt, rowp);
    hipMemsetAsync(cnt, 0, (size_t)N * 4, stream);
    k_scatter<<<(E + 255) / 256, 256, 0, stream>>>(eidx, rowp, cnt, perm);
    k_msg<1><<<1536, 256, 0, stream>>>(s1, v1f, emb, sh0, sh1, eidx, Wm1, Wm2,
                                       w2sTg, w2vTg, nullptr, nullptr, msgS, msgV);
    float* aggs = s1;    // s1/v1 dead after k_msg: alias
    float* aggv = v1f;
    k_agg<<<N / 4, 256, 0, stream>>>(msgS, msgV, rowp, perm, aggs, aggv);
    k_c1<<<1563, 256, 0, stream>>>(node_s, attrs, aggs, Wt0, BT, (float*)d_out, gts);
    k_c2<<<1563, 256, 0, stream>>>(node_v, attrs, aggv, Wt1, B2T, gts, (float*)d_out);
  } else {
    float* aggs = (float*)pmode;
    float* aggv = aggs + (size_t)N * 64;
    hipMemsetAsync(aggs, 0, (size_t)N * 160 * 4, stream);
    k_msg<0><<<1536, 256, 0, stream>>>(s1, v1f, emb, sh0, sh1, eidx, Wm1, Wm2,
                                       w2sTg, w2vTg, aggs, aggv, nullptr, nullptr);
    k_c1<<<1563, 256, 0, stream>>>(node_s, attrs, aggs, Wt0, BT, (float*)d_out, gts);
    k_c2<<<1563, 256, 0, stream>>>(node_v, attrs, aggv, Wt1, B2T, gts, (float*)d_out);
  }
}

// Round 4
// 753.932 us; speedup vs baseline: 1.6259x; 1.2319x over previous
//
#include <hip/hip_runtime.h>
#include <math.h>

#define N 50000
#define E 600000
#define EPB 16     // edges per pass
#define LDK 104    // padded K stride (bf16 elems) for tp tiles

typedef __attribute__((ext_vector_type(8))) short short8;
typedef __attribute__((ext_vector_type(4))) float float4v;

__device__ __forceinline__ float silu_f(float x) { return x / (1.f + __expf(-x)); }
__device__ __forceinline__ float sigm_f(float x) { return 1.f / (1.f + __expf(-x)); }
__device__ __forceinline__ unsigned short f2bf(float f) {
  unsigned u = __float_as_uint(f);
  u += 0x7fff + ((u >> 16) & 1);   // RNE
  return (unsigned short)(u >> 16);
}
__device__ __forceinline__ float bf2f(unsigned short u) {
  return __uint_as_float(((unsigned)u) << 16);
}

// ---------------- CSR build ----------------
__global__ void k_hist(const int* __restrict__ eidx, int* __restrict__ counts) {
  int e = blockIdx.x * 256 + threadIdx.x;
  if (e < E) atomicAdd(&counts[eidx[E + e]], 1);
}

__global__ __launch_bounds__(1024)
void k_scan(const int* __restrict__ counts, int* __restrict__ row_ptr) {
  __shared__ int ssum[1024];
  const int t = threadIdx.x;
  const int CH = 49;
  int lo = t * CH, hi = min(lo + CH, N);
  int s = 0;
  for (int i = lo; i < hi; i++) s += counts[i];
  ssum[t] = s;
  __syncthreads();
  for (int off = 1; off < 1024; off <<= 1) {
    int v = (t >= off) ? ssum[t - off] : 0;
    __syncthreads();
    ssum[t] += v;
    __syncthreads();
  }
  int run = (t == 0) ? 0 : ssum[t - 1];
  for (int i = lo; i < hi; i++) { row_ptr[i] = run; run += counts[i]; }
  if (t == 1023) row_ptr[N] = ssum[1023];
}

__global__ void k_scatter(const int* __restrict__ eidx, const int* __restrict__ row_ptr,
                          int* __restrict__ woff, int* __restrict__ perm) {
  int e = blockIdx.x * 256 + threadIdx.x;
  if (e < E) {
    int d = eidx[E + e];
    int p = atomicAdd(&woff[d], 1);
    perm[row_ptr[d] + p] = e;
  }
}

// ---------------- weight prep: bf16 transposed B matrices ----------------
// w2sTg [96][96] / w2vTg [32][96] (isq96 folded): k_msg hoists its MFMA
// B-fragments from these into registers once, before the pass loop.
__global__ void k_prep(const float* __restrict__ Wsc0, const float* __restrict__ W3s,
                       const float* __restrict__ Wsc1, const float* __restrict__ W3v,
                       const float* __restrict__ W2s, const float* __restrict__ W2v,
                       unsigned short* __restrict__ BT, unsigned short* __restrict__ B2T,
                       unsigned short* __restrict__ w2sTg, unsigned short* __restrict__ w2vTg) {
  const float isq96 = 0.10206207261596575f;
  int i = blockIdx.x * 256 + threadIdx.x;
  if (i < 96 * 1088) {
    int j = i / 1088, k = i % 1088;
    float v;
    if (k < 1024) v = Wsc0[(size_t)k * 96 + j] * 0.03125f;          // 1/sqrt(1024)
    else          v = W3s[(size_t)(k - 1024) * 96 + j] * 0.125f;    // 1/sqrt(64)
    BT[i] = f2bf(v);
  } else if (i < 96 * 1088 + 32 * 576) {
    int i2 = i - 96 * 1088;
    int w = i2 / 576, k = i2 % 576;
    float v = 0.f;
    if (k < 512)      v = Wsc1[(size_t)k * 32 + w] * 0.04419417382415922f;  // 1/sqrt(512)
    else if (k < 544) v = W3v[(size_t)(k - 512) * 32 + w] * 0.17677669529663689f; // 1/sqrt(32)
    B2T[i2] = f2bf(v);
  } else if (i < 96 * 1088 + 32 * 576 + 96 * 96) {
    int i3 = i - (96 * 1088 + 32 * 576);
    int j = i3 / 96, k = i3 % 96;            // w2sTg[j][k] = W2s[k][j]
    w2sTg[i3] = f2bf(W2s[(size_t)k * 96 + j] * isq96);
  } else {
    int i4 = i - (96 * 1088 + 32 * 576 + 96 * 96);
    if (i4 < 32 * 96) {
      int v = i4 / 96, u = i4 % 96;          // w2vTg[v][u] = W2v[u][v]
      w2vTg[i4] = f2bf(W2v[(size_t)u * 32 + v] * isq96);
    }
  }
}

// ---------------- Kernel A: s1 = node_s@W1s/8 ; v1 = node_v x W1v /sqrt(32) ----------------
__global__ __launch_bounds__(256, 4)
void k_lin1(const float* __restrict__ node_s, const float* __restrict__ node_v,
            const float* __restrict__ W1s, const float* __restrict__ W1v,
            float* __restrict__ s1, float* __restrict__ v1) {
  __shared__ float w1s[64 * 64];
  __shared__ float w1v[32 * 32];
  for (int i = threadIdx.x; i < 64 * 64; i += 256) w1s[i] = W1s[i];
  for (int i = threadIdx.x; i < 32 * 32; i += 256) w1v[i] = W1v[i];
  __syncthreads();
  const float is_ns = 0.125f;
  const float is_nv = 0.17677669529663689f;
  int gtid = blockIdx.x * 256 + threadIdx.x;
  int stride = gridDim.x * 256;
  for (int i = gtid; i < N * 160; i += stride) {
    int n = i / 160, ch = i % 160;
    if (ch < 64) {
      const float* row = node_s + n * 64;
      float acc = 0.f;
#pragma unroll
      for (int u = 0; u < 64; u++) acc += row[u] * w1s[u * 64 + ch];
      s1[n * 64 + ch] = acc * is_ns;
    } else {
      int p = ch - 64, v = p / 3, c = p % 3;
      const float* row = node_v + n * 96;
      float acc = 0.f;
#pragma unroll
      for (int u = 0; u < 32; u++) acc += row[u * 3 + c] * w1v[u * 32 + v];
      v1[n * 96 + p] = acc * is_nv;
    }
  }
}

// ---------------- Kernel B: streaming per-edge message via MFMA ----------------
// R0 structure (EPB=16, 256 threads) with two evidence-backed changes:
// 1. MFMA B-fragments hoisted into REGISTERS before the pass loop (9 short8
//    = 36 VGPRs; wave symmetry: GEMM2's nt2 = wave&1 for both its tiles).
//    -> no per-pass B reads at all (R0 paid LDS+conflicts; R3 paid global lat).
// 2. Wm2 weights stay in LDS (wm2s) and phase B reads them EXPLICITLY from
//    LDS -- the "register cache" never fit (VGPR 84 < 96 floats) and R3's
//    removal of wm2s demoted it to per-pass GLOBAL loads (the 375us regression).
// LDS 50.2KB -> 23.5KB; __launch_bounds__(256,4) caps VGPR at 128 -> 4 blk/CU.
template<int STORE>
__global__ __launch_bounds__(256, 4)
void k_msg(const float* __restrict__ s1, const float* __restrict__ v1,
           const float* __restrict__ emb, const float* __restrict__ sh0g,
           const float* __restrict__ sh1g, const int* __restrict__ eidx,
           const float* __restrict__ Wm1, const float* __restrict__ Wm2,
           const unsigned short* __restrict__ w2sTg, const unsigned short* __restrict__ w2vTg,
           float* __restrict__ aggs, float* __restrict__ aggv,
           unsigned short* __restrict__ msgS, unsigned short* __restrict__ msgV) {
  __shared__ float wm2s[192 * 9];             // staging, stride 9 (bank-safe)
  __shared__ float wm1s[64];
  __shared__ unsigned short tps[EPB * LDK];
  __shared__ unsigned short tpv[EPB * 3 * LDK];
  __shared__ float gat[EPB][33];              // padded: bank-conflict-free
  __shared__ float hb[EPB][8];
  __shared__ float sh1b[EPB][4];
  __shared__ float sh0b[EPB];
  __shared__ int ssrc[EPB];
  __shared__ int sdst[EPB];

  const int t = threadIdx.x;
  const int wave = t >> 6, lane = t & 63;
  const int lm = lane & 15, quad = lane >> 4;
  const int subc = t & 15;

  // ---- one-time staging ----
  for (int i = t; i < 192 * 8; i += 256) {
    int h = i / 192, c = i % 192;
    wm2s[c * 9 + h] = Wm2[i];
  }
  if (t < 64) wm1s[t] = Wm1[t];

  // ---- hoist MFMA B-fragments into registers (pass-invariant) ----
  short8 b1fr[2][3], b2fr[3];
  {
    const int nt0 = wave;
    const int nt1 = (wave + 4 < 6) ? wave + 4 : wave;   // waves 2,3: dup (unused)
    const int nv2 = wave & 1;                           // GEMM2: same for both tiles
#pragma unroll
    for (int kk = 0; kk < 3; kk++) {
      b1fr[0][kk] = *(const short8*)&w2sTg[(nt0 * 16 + lm) * 96 + kk * 32 + quad * 8];
      b1fr[1][kk] = *(const short8*)&w2sTg[(nt1 * 16 + lm) * 96 + kk * 32 + quad * 8];
      b2fr[kk]    = *(const short8*)&w2vTg[(nv2 * 16 + lm) * 96 + kk * 32 + quad * 8];
    }
  }
  __syncthreads();

  for (int pass = blockIdx.x; pass < E / EPB; pass += gridDim.x) {
    const int ebase = pass * EPB;
    __syncthreads();
    // ---- phase A: stage edge meta + radial MLP hidden (disjoint threads) ----
    if (t < EPB) {
      ssrc[t] = eidx[ebase + t];
      if (!STORE) sdst[t] = eidx[E + ebase + t];
      sh0b[t] = sh0g[ebase + t];
    } else if (t >= 64 && t < 64 + EPB * 3) {
      int i = t - 64;
      sh1b[i / 3][i % 3] = sh1g[ebase * 3 + i];
    } else if (t >= 128) {
      int i = t - 128, el = i >> 3, sub = i & 7;
      float acc = 0.f;
#pragma unroll
      for (int r = 0; r < 8; r++) acc += emb[(ebase + el) * 8 + r] * wm1s[r * 8 + sub];
      hb[el][sub] = silu_f(acc);
    }
    __syncthreads();
    // ---- phase B: build TPS / TPV (bf16); Wm2 read explicitly from LDS ----
    {
      const int el = t >> 4, sub = subc;
      const int src = ssrc[el];
      const float s0v = sh0b[el];
      const float x0 = sh1b[el][0], x1 = sh1b[el][1], x2 = sh1b[el][2];
      float hr[8];
#pragma unroll
      for (int h = 0; h < 8; h++) hr[h] = hb[el][h];
      const float4v ss = *(const float4v*)&s1[(size_t)src * 64 + sub * 4];
      unsigned short tsv[4], tvv[3][4];
#pragma unroll
      for (int i = 0; i < 4; i++) {
        float w0a = 0.f, w1a = 0.f;
#pragma unroll
        for (int h = 0; h < 8; h++) {
          w0a += hr[h] * wm2s[(sub * 4 + i) * 9 + h];
          w1a += hr[h] * wm2s[(64 + sub * 4 + i) * 9 + h];
        }
        const float ssu = ss[i];
        tsv[i] = f2bf(w0a * ssu * s0v);
        const float base = w1a * ssu;
        tvv[0][i] = f2bf(base * x0);
        tvv[1][i] = f2bf(base * x1);
        tvv[2][i] = f2bf(base * x2);
      }
      *(uint2*)&tps[el * LDK + sub * 4] = *(uint2*)tsv;
#pragma unroll
      for (int c = 0; c < 3; c++)
        *(uint2*)&tpv[(el * 3 + c) * LDK + sub * 4] = *(uint2*)tvv[c];
      const float2* vp = (const float2*)&v1[(size_t)src * 96 + sub * 6];
      const float2 va = vp[0], vb = vp[1], vc = vp[2];
      const float v6[6] = {va.x, va.y, vb.x, vb.y, vc.x, vc.y};
      unsigned short ts2[2], tv2[3][2];
#pragma unroll
      for (int i2 = 0; i2 < 2; i2++) {
        float w1b = 0.f, w0b = 0.f;
#pragma unroll
        for (int h = 0; h < 8; h++) {
          w1b += hr[h] * wm2s[(128 + sub * 2 + i2) * 9 + h];
          w0b += hr[h] * wm2s[(160 + sub * 2 + i2) * 9 + h];
        }
        const float vx = v6[i2 * 3 + 0], vy = v6[i2 * 3 + 1], vz = v6[i2 * 3 + 2];
        ts2[i2] = f2bf(w0b * (vx * x0 + vy * x1 + vz * x2));
        tv2[0][i2] = f2bf(w1b * vx * s0v);
        tv2[1][i2] = f2bf(w1b * vy * s0v);
        tv2[2][i2] = f2bf(w1b * vz * s0v);
      }
      *(unsigned*)&tps[el * LDK + 64 + sub * 2] = *(unsigned*)ts2;
#pragma unroll
      for (int c = 0; c < 3; c++)
        *(unsigned*)&tpv[(el * 3 + c) * LDK + 64 + sub * 2] = *(unsigned*)tv2[c];
    }
    __syncthreads();
    // ---- GEMM1: m_s[16][96] (B from registers) ----
    {
      short8 afr[3];
#pragma unroll
      for (int kk = 0; kk < 3; kk++)
        afr[kk] = *(const short8*)&tps[lm * LDK + kk * 32 + quad * 8];
#pragma unroll
      for (int t2 = 0; t2 < 2; t2++) {
        const int nt = wave + t2 * 4;
        if (nt < 6) {
          float4v acc = {0.f, 0.f, 0.f, 0.f};
#pragma unroll
          for (int kk = 0; kk < 3; kk++)
            acc = __builtin_amdgcn_mfma_f32_16x16x32_bf16(afr[kk], b1fr[t2][kk], acc, 0, 0, 0);
          const int j = nt * 16 + lm;
#pragma unroll
          for (int reg = 0; reg < 4; reg++) {
            const int e = quad * 4 + reg;
            const float val = acc[reg];
            if (j < 64) {
              if (STORE) msgS[(size_t)(ebase + e) * 64 + j] = f2bf(silu_f(val));
              else atomicAdd(&aggs[(size_t)sdst[e] * 64 + j], silu_f(val));
            } else {
              gat[e][j - 64] = sigm_f(val);
            }
          }
        }
      }
    }
    __syncthreads();
    // ---- GEMM2: m_v[48][32] (B from registers) ----
#pragma unroll
    for (int t2 = 0; t2 < 2; t2++) {
      const int tile = wave + t2 * 4;
      if (tile < 6) {
        const int mt = tile >> 1, nt2 = tile & 1;
        float4v acc = {0.f, 0.f, 0.f, 0.f};
#pragma unroll
        for (int kk = 0; kk < 3; kk++) {
          short8 a = *(const short8*)&tpv[(mt * 16 + lm) * LDK + kk * 32 + quad * 8];
          acc = __builtin_amdgcn_mfma_f32_16x16x32_bf16(a, b2fr[kk], acc, 0, 0, 0);
        }
        const int v = nt2 * 16 + lm;
#pragma unroll
        for (int reg = 0; reg < 4; reg++) {
          const int r = mt * 16 + quad * 4 + reg;
          const int e = (r * 171) >> 9, c = r - 3 * e;
          const float val = acc[reg] * gat[e][v];
          if (STORE) msgV[(size_t)(ebase + e) * 96 + v * 3 + c] = f2bf(val);
          else atomicAdd(&aggv[(size_t)sdst[e] * 96 + v * 3 + c], val);
        }
      }
    }
  }
}

// ---------------- Kernel B2: wave-per-node gather-reduction via perm ----------------
__global__ __launch_bounds__(256, 8)
void k_agg(const unsigned short* __restrict__ msgS, const unsigned short* __restrict__ msgV,
           const int* __restrict__ rowp, const int* __restrict__ perm,
           float* __restrict__ aggs, float* __restrict__ aggv) {
  const int wv = threadIdx.x >> 6, lane = threadIdx.x & 63;
  const int n = blockIdx.x * 4 + wv;
  const int lo = rowp[n], hi = rowp[n + 1];
  float sS = 0.f, v0 = 0.f, v1a = 0.f;
  int r = lo;
  for (; r + 2 <= hi; r += 2) {
    const int e0 = perm[r], e1 = perm[r + 1];
    const unsigned short a0 = msgS[(size_t)e0 * 64 + lane];
    const unsigned short a1 = msgS[(size_t)e1 * 64 + lane];
    const unsigned short b0 = msgV[(size_t)e0 * 96 + lane];
    const unsigned short b1 = msgV[(size_t)e1 * 96 + lane];
    unsigned short c0 = 0, c1 = 0;
    if (lane < 32) {
      c0 = msgV[(size_t)e0 * 96 + 64 + lane];
      c1 = msgV[(size_t)e1 * 96 + 64 + lane];
    }
    sS += bf2f(a0) + bf2f(a1);
    v0 += bf2f(b0) + bf2f(b1);
    v1a += bf2f(c0) + bf2f(c1);
  }
  for (; r < hi; r++) {
    const int e0 = perm[r];
    sS += bf2f(msgS[(size_t)e0 * 64 + lane]);
    v0 += bf2f(msgV[(size_t)e0 * 96 + lane]);
    if (lane < 32) v1a += bf2f(msgV[(size_t)e0 * 96 + 64 + lane]);
  }
  aggs[(size_t)n * 64 + lane] = sS;
  aggv[(size_t)n * 96 + lane] = v0;
  if (lane < 32) aggv[(size_t)n * 96 + 64 + lane] = v1a;
}

// ---------------- Kernel C1: MFMA GEMM  [32 nodes x 1088] @ BT^T -> 96 cols ----------------
__global__ __launch_bounds__(256, 4)
void k_c1(const float* __restrict__ node_s, const float* __restrict__ attrs,
          const float* __restrict__ aggs, const float* __restrict__ Wt0,
          const unsigned short* __restrict__ BT,
          float* __restrict__ out, float* __restrict__ gates) {
  __shared__ float s_row[32][64];
  __shared__ float attr[32][16];
  __shared__ float t0[32][64];
  __shared__ float wt0[1024];
  __shared__ unsigned short As[32 * 72];
  const int t = threadIdx.x;
  const int wave = t >> 6, lane = t & 63, lm = lane & 15, quad = lane >> 4;
  const int nbase = blockIdx.x * 32;

  for (int i = t; i < 1024; i += 256) wt0[i] = Wt0[i];
  for (int i = t; i < 2048; i += 256) {
    int nl = i >> 6, u = i & 63, n = nbase + nl;
    s_row[nl][u] = (n < N) ? node_s[(size_t)n * 64 + u] : 0.f;
    t0[nl][u]    = (n < N) ? aggs[(size_t)n * 64 + u] : 0.f;
  }
  for (int i = t; i < 512; i += 256) {
    int nl = i >> 4, a = i & 15, n = nbase + nl;
    attr[nl][a] = (n < N) ? attrs[(size_t)n * 16 + a] : 0.f;
  }
  __syncthreads();
  for (int i = t; i < 2048; i += 256) {
    int nl = i >> 6, u = i & 63;
    float d0 = 0.f;
#pragma unroll
    for (int a = 0; a < 16; a++) d0 += attr[nl][a] * wt0[u * 16 + a];
    t0[nl][u] *= d0 * 0.07216878364870322f;   // 1/(sqrt(16)*sqrt(12))
  }

  float4v acc[3] = {{0,0,0,0},{0,0,0,0},{0,0,0,0}};
  int mts[3], nts[3];
#pragma unroll
  for (int tt = 0; tt < 3; tt++) {
    const int tile = wave + tt * 4;    // 0..11 = mt*6+nt
    mts[tt] = tile / 6;
    nts[tt] = tile % 6;
  }

  for (int kc = 0; kc < 17; kc++) {
    __syncthreads();
    {
      const int row = t >> 3, c0 = (t & 7) * 8;
      unsigned short tmp[8];
      if (kc < 16) {
        const int u = kc * 4 + (c0 >> 4);
        const float sval = s_row[row][u];
        const int ab = c0 & 8;
#pragma unroll
        for (int i = 0; i < 8; i++) tmp[i] = f2bf(sval * attr[row][ab + i]);
      } else {
#pragma unroll
        for (int i = 0; i < 8; i++) tmp[i] = f2bf(t0[row][c0 + i]);
      }
      *(uint4*)&As[row * 72 + c0] = *(uint4*)tmp;
    }
    __syncthreads();
#pragma unroll
    for (int ks = 0; ks < 2; ks++) {
      short8 am0 = *(const short8*)&As[(lm) * 72 + ks * 32 + quad * 8];
      short8 am1 = *(const short8*)&As[(16 + lm) * 72 + ks * 32 + quad * 8];
#pragma unroll
      for (int tt = 0; tt < 3; tt++) {
        short8 b = *(const short8*)&BT[(size_t)(nts[tt] * 16 + lm) * 1088 + kc * 64 + ks * 32 + quad * 8];
        acc[tt] = __builtin_amdgcn_mfma_f32_16x16x32_bf16(mts[tt] ? am1 : am0, b, acc[tt], 0, 0, 0);
      }
    }
  }
#pragma unroll
  for (int tt = 0; tt < 3; tt++) {
    const int j = nts[tt] * 16 + lm;
#pragma unroll
    for (int reg = 0; reg < 4; reg++) {
      const int m = mts[tt] * 16 + quad * 4 + reg;
      const int n = nbase + m;
      if (n < N) {
        const float val = acc[tt][reg];
        if (j < 64) out[(size_t)n * 160 + j] = silu_f(val);
        else        gates[(size_t)n * 32 + (j - 64)] = sigm_f(val);
      }
    }
  }
}

// ---------------- Kernel C2: MFMA GEMM  [96 rows (32n x 3c) x 544] @ B2T^T -> 32 cols ----------------
__global__ __launch_bounds__(256, 3)
void k_c2(const float* __restrict__ node_v, const float* __restrict__ attrs,
          const float* __restrict__ aggv, const float* __restrict__ Wt1,
          const unsigned short* __restrict__ B2T, const float* __restrict__ gts,
          float* __restrict__ out) {
  __shared__ float nvs[32][96];
  __shared__ float t1s[32][96];
  __shared__ float attr[32][16];
  __shared__ float wt1[512];
  __shared__ unsigned short As2[96 * 72];
  const int t = threadIdx.x;
  const int wave = t >> 6, lane = t & 63, lm = lane & 15, quad = lane >> 4;
  const int nbase = blockIdx.x * 32;

  for (int i = t; i < 512; i += 256) wt1[i] = Wt1[i];
  for (int i = t; i < 32 * 96; i += 256) {
    int nl = i / 96, rr = i % 96, n = nbase + nl;
    nvs[nl][rr] = (n < N) ? node_v[(size_t)n * 96 + rr] : 0.f;
    t1s[nl][rr] = (n < N) ? aggv[(size_t)n * 96 + rr] : 0.f;
  }
  for (int i = t; i < 512; i += 256) {
    int nl = i >> 4, a = i & 15, n = nbase + nl;
    attr[nl][a] = (n < N) ? attrs[(size_t)n * 16 + a] : 0.f;
  }
  __syncthreads();
  for (int i = t; i < 1024; i += 256) {
    int nl = i >> 5, u = i & 31;
    float d1 = 0.f;
#pragma unroll
    for (int a = 0; a < 16; a++) d1 += attr[nl][a] * wt1[u * 16 + a];
    d1 *= 0.07216878364870322f;
    t1s[nl][u * 3 + 0] *= d1; t1s[nl][u * 3 + 1] *= d1; t1s[nl][u * 3 + 2] *= d1;
  }

  float4v acc[3] = {{0,0,0,0},{0,0,0,0},{0,0,0,0}};
  int mts[3], nts[3];
#pragma unroll
  for (int tt = 0; tt < 3; tt++) {
    const int tile = wave + tt * 4;   // 0..11 = mt*2+nt
    mts[tt] = tile >> 1;
    nts[tt] = tile & 1;
  }

  for (int kc = 0; kc < 9; kc++) {
    __syncthreads();
#pragma unroll
    for (int jj = 0; jj < 3; jj++) {
      const int job = t + jj * 256;
      const int row = job >> 3, c0 = (job & 7) * 8;
      const int nl = (row * 171) >> 9, c = row - 3 * nl;
      const int kbase = kc * 64 + c0;
      unsigned short tmp[8];
      if (kbase < 512) {
        const int u = kbase >> 4;
        const float vval = nvs[nl][u * 3 + c];
        const int ab = c0 & 8;
#pragma unroll
        for (int i = 0; i < 8; i++) tmp[i] = f2bf(vval * attr[nl][ab + i]);
      } else if (kbase < 544) {
        const int u2 = kbase - 512;
#pragma unroll
        for (int i = 0; i < 8; i++) tmp[i] = f2bf(t1s[nl][(u2 + i) * 3 + c]);
      } else {
#pragma unroll
        for (int i = 0; i < 8; i++) tmp[i] = 0;
      }
      *(uint4*)&As2[row * 72 + c0] = *(uint4*)tmp;
    }
    __syncthreads();
#pragma unroll
    for (int ks = 0; ks < 2; ks++) {
#pragma unroll
      for (int tt = 0; tt < 3; tt++) {
        short8 a = *(const short8*)&As2[(mts[tt] * 16 + lm) * 72 + ks * 32 + quad * 8];
        short8 b = *(const short8*)&B2T[(size_t)(nts[tt] * 16 + lm) * 576 + kc * 64 + ks * 32 + quad * 8];
        acc[tt] = __builtin_amdgcn_mfma_f32_16x16x32_bf16(a, b, acc[tt], 0, 0, 0);
      }
    }
  }
#pragma unroll
  for (int tt = 0; tt < 3; tt++) {
    const int w = nts[tt] * 16 + lm;
#pragma unroll
    for (int reg = 0; reg < 4; reg++) {
      const int row = mts[tt] * 16 + quad * 4 + reg;
      const int nl = (row * 171) >> 9, c = row - 3 * nl;
      const int n = nbase + nl;
      if (n < N)
        out[(size_t)n * 160 + 64 + w * 3 + c] = acc[tt][reg] * gts[(size_t)n * 32 + w];
    }
  }
}

extern "C" void kernel_launch(void* const* d_in, const int* in_sizes, int n_in,
                              void* d_out, int out_size, void* d_ws, size_t ws_size,
                              hipStream_t stream) {
  const float* node_s = (const float*)d_in[0];
  const float* node_v = (const float*)d_in[1];
  const float* attrs  = (const float*)d_in[2];
  const float* emb    = (const float*)d_in[3];
  const float* sh0    = (const float*)d_in[4];
  const float* sh1    = (const float*)d_in[5];
  const int*   eidx   = (const int*)d_in[6];
  const float* W1s    = (const float*)d_in[7];
  const float* W1v    = (const float*)d_in[8];
  const float* Wm1    = (const float*)d_in[9];
  const float* Wm2    = (const float*)d_in[10];
  const float* W2s    = (const float*)d_in[11];
  const float* W2v    = (const float*)d_in[12];
  const float* Wt0    = (const float*)d_in[13];
  const float* Wt1    = (const float*)d_in[14];
  const float* W3s    = (const float*)d_in[15];
  const float* W3v    = (const float*)d_in[16];
  const float* Wsc0   = (const float*)d_in[17];
  const float* Wsc1   = (const float*)d_in[18];

  char* p = (char*)d_ws;
  float* s1  = (float*)p;  p += (size_t)N * 64 * 4;
  float* v1f = (float*)p;  p += (size_t)N * 96 * 4;
  float* gts = (float*)p;  p += (size_t)N * 32 * 4;
  unsigned short* BT    = (unsigned short*)p;  p += (size_t)96 * 1088 * 2;
  unsigned short* B2T   = (unsigned short*)p;  p += (size_t)32 * 576 * 2;
  unsigned short* w2sTg = (unsigned short*)p;  p += (size_t)96 * 96 * 2;
  unsigned short* w2vTg = (unsigned short*)p;  p += (size_t)32 * 96 * 2;
  char* pmode = p;
  size_t base = (size_t)(pmode - (char*)d_ws);
  size_t need_store = base + ((size_t)N + 1) * 4 + (size_t)N * 4 + (size_t)E * 4
                    + (size_t)E * 64 * 2 + (size_t)E * 96 * 2;
  const bool store = (ws_size >= need_store);

  k_prep<<<528, 256, 0, stream>>>(Wsc0, W3s, Wsc1, W3v, W2s, W2v, BT, B2T, w2sTg, w2vTg);
  k_lin1<<<1024, 256, 0, stream>>>(node_s, node_v, W1s, W1v, s1, v1f);

  if (store) {
    int* rowp = (int*)pmode;
    int* cnt  = rowp + (N + 1);
    int* perm = cnt + N;
    unsigned short* msgS = (unsigned short*)(perm + E);
    unsigned short* msgV = msgS + (size_t)E * 64;
    hipMemsetAsync(cnt, 0, (size_t)N * 4, stream);
    k_hist<<<(E + 255) / 256, 256, 0, stream>>>(eidx, cnt);
    k_scan<<<1, 1024, 0, stream>>>(cnt, rowp);
    hipMemsetAsync(cnt, 0, (size_t)N * 4, stream);
    k_scatter<<<(E + 255) / 256, 256, 0, stream>>>(eidx, rowp, cnt, perm);
    k_msg<1><<<1024, 256, 0, stream>>>(s1, v1f, emb, sh0, sh1, eidx, Wm1, Wm2,
                                       w2sTg, w2vTg, nullptr, nullptr, msgS, msgV);
    float* aggs = s1;    // s1/v1 dead after k_msg: alias
    float* aggv = v1f;
    k_agg<<<N / 4, 256, 0, stream>>>(msgS, msgV, rowp, perm, aggs, aggv);
    k_c1<<<1563, 256, 0, stream>>>(node_s, attrs, aggs, Wt0, BT, (float*)d_out, gts);
    k_c2<<<1563, 256, 0, stream>>>(node_v, attrs, aggv, Wt1, B2T, gts, (float*)d_out);
  } else {
    float* aggs = (float*)pmode;
    float* aggv = aggs + (size_t)N * 64;
    hipMemsetAsync(aggs, 0, (size_t)N * 160 * 4, stream);
    k_msg<0><<<1024, 256, 0, stream>>>(s1, v1f, emb, sh0, sh1, eidx, Wm1, Wm2,
                                       w2sTg, w2vTg, aggs, aggv, nullptr, nullptr);
    k_c1<<<1563, 256, 0, stream>>>(node_s, attrs, aggs, Wt0, BT, (float*)d_out, gts);
    k_c2<<<1563, 256, 0, stream>>>(node_v, attrs, aggv, Wt1, B2T, gts, (float*)d_out);
  }
}